// Round 1
// baseline (1929.031 us; speedup 1.0000x reference)
//
#include <hip/hip_runtime.h>

#define H 128
#define EPSILON 0.7071067811865476f
#define NEPS 1e-8f
#define NT3 12

__device__ __forceinline__ float silu_f(float x) {
    return x / (1.0f + __expf(-x));
}

// ---------------- K0: init d_out[n][0][h] = s, d_out[n][1+d][h] = v ----------------
__global__ void k0_init(const float4* __restrict__ s, const float4* __restrict__ v,
                        float4* __restrict__ out, int n_nodes) {
    int i = blockIdx.x * blockDim.x + threadIdx.x;
    int total = n_nodes * 128;   // 512 floats per node = 128 float4
    if (i >= total) return;
    int n = i >> 7, r = i & 127;
    float4 val;
    if (r < 32) val = s[n * 32 + r];         // s row: 128 floats = 32 float4
    else        val = v[n * 96 + (r - 32)];  // v row: 384 floats = 96 float4
    out[i] = val;
}

// ---------------- K1: x = silu(s@Wi1 + bi1) @ Wi2 + bi2, per node ----------------
__global__ __launch_bounds__(128) void k1_mlp_x(
        const float* __restrict__ s,
        const float* __restrict__ Wi1, const float* __restrict__ bi1,
        const float* __restrict__ Wi2, const float* __restrict__ bi2,
        float* __restrict__ x, int n_nodes) {
    __shared__ float s_lds[32][H];
    __shared__ float h_lds[32][H];
    int j = threadIdx.x;           // 0..127
    int node0 = blockIdx.x * 32;

    #pragma unroll
    for (int n = 0; n < 32; ++n) {
        int node = node0 + n; if (node >= n_nodes) node = n_nodes - 1;
        s_lds[n][j] = s[(size_t)node * H + j];
    }
    __syncthreads();

    float acc[32];
    #pragma unroll
    for (int n = 0; n < 32; ++n) acc[n] = bi1[j];
    for (int k = 0; k < H; k += 4) {
        float w0 = Wi1[(k + 0) * H + j];
        float w1 = Wi1[(k + 1) * H + j];
        float w2 = Wi1[(k + 2) * H + j];
        float w3 = Wi1[(k + 3) * H + j];
        #pragma unroll
        for (int n = 0; n < 32; ++n) {
            float4 sv = *reinterpret_cast<const float4*>(&s_lds[n][k]);
            acc[n] += sv.x * w0 + sv.y * w1 + sv.z * w2 + sv.w * w3;
        }
    }
    #pragma unroll
    for (int n = 0; n < 32; ++n) h_lds[n][j] = silu_f(acc[n]);
    __syncthreads();

    for (int c = 0; c < 3; ++c) {
        int col = c * H + j;
        float a2[32];
        #pragma unroll
        for (int n = 0; n < 32; ++n) a2[n] = bi2[col];
        for (int k = 0; k < H; k += 4) {
            float w0 = Wi2[(k + 0) * 384 + col];
            float w1 = Wi2[(k + 1) * 384 + col];
            float w2 = Wi2[(k + 2) * 384 + col];
            float w3 = Wi2[(k + 3) * 384 + col];
            #pragma unroll
            for (int n = 0; n < 32; ++n) {
                float4 hv = *reinterpret_cast<const float4*>(&h_lds[n][k]);
                a2[n] += hv.x * w0 + hv.y * w1 + hv.z * w2 + hv.w * w3;
            }
        }
        #pragma unroll
        for (int n = 0; n < 32; ++n) {
            int node = node0 + n;
            if (node < n_nodes) x[(size_t)node * 384 + col] = a2[n];
        }
    }
}

// ---------------- K2: edge messages, scatter-add into d_out ----------------
__global__ __launch_bounds__(256) void k2_edges(
        const float* __restrict__ x, const float* __restrict__ v,
        const float* __restrict__ dir, const float* __restrict__ Wij,
        const int* __restrict__ senders, const int* __restrict__ receivers,
        float* __restrict__ out, int n_edges) {
    int e = blockIdx.x * 2 + (threadIdx.x >> 7);
    int h = threadIdx.x & 127;
    if (e >= n_edges) return;
    int r   = receivers[e];
    int snd = senders[e];
    const float* xr = x   + (size_t)r * 384;
    const float* we = Wij + (size_t)e * 384;
    float ds  = we[h]       * xr[h];
    float dv1 = we[128 + h] * xr[128 + h];
    float dv2 = we[256 + h] * xr[256 + h];
    float d0 = dir[(size_t)e * 3 + 0];
    float d1 = dir[(size_t)e * 3 + 1];
    float d2 = dir[(size_t)e * 3 + 2];
    const float* vr = v + (size_t)r * 384;
    float* o = out + (size_t)snd * 512;
    unsafeAtomicAdd(&o[h],          ds);
    unsafeAtomicAdd(&o[128 + h],    dv1 * d0 + dv2 * vr[h]);
    unsafeAtomicAdd(&o[256 + h],    dv1 * d1 + dv2 * vr[128 + h]);
    unsafeAtomicAdd(&o[384 + h],    dv1 * d2 + dv2 * vr[256 + h]);
}

// ---------------- K3: per-node update (reads accumulated d_out, rewrites it) ----------------
__global__ __launch_bounds__(256) void k3_update(
        const float* __restrict__ Wvm,
        const float* __restrict__ Wm1, const float* __restrict__ bm1,
        const float* __restrict__ Wm2, const float* __restrict__ bm2,
        float* __restrict__ out, int n_nodes) {
    __shared__ float v_lds[NT3][3][H];    // v_mid
    __shared__ float vl_lds[NT3][3][H];   // v_l
    __shared__ float ts_lds[NT3][2 * H];  // [s_mid | v_norm -> h1]
    __shared__ float dot_lds[NT3][H];     // sum_d v_r*v_l
    int t = threadIdx.x;     // 0..255
    int node0 = blockIdx.x * NT3;

    for (int idx = t; idx < NT3 * 512; idx += 256) {
        int n = idx >> 9, r = idx & 511;
        int node = node0 + n; if (node >= n_nodes) node = n_nodes - 1;
        float val = out[(size_t)node * 512 + r] * EPSILON;
        if (r < 128) ts_lds[n][r] = val;
        else         v_lds[n][(r >> 7) - 1][r & 127] = val;
    }
    __syncthreads();

    // vW = v_mid @ Wvm  : thread t owns output column t (0..255)
    float acc[NT3 * 3];
    #pragma unroll
    for (int i = 0; i < NT3 * 3; ++i) acc[i] = 0.f;
    int j = t;
    for (int k = 0; k < H; k += 4) {
        float w0 = Wvm[(k + 0) * 256 + j];
        float w1 = Wvm[(k + 1) * 256 + j];
        float w2 = Wvm[(k + 2) * 256 + j];
        float w3 = Wvm[(k + 3) * 256 + j];
        #pragma unroll
        for (int n = 0; n < NT3; ++n) {
            #pragma unroll
            for (int d = 0; d < 3; ++d) {
                float4 vv = *reinterpret_cast<const float4*>(&v_lds[n][d][k]);
                acc[n * 3 + d] += vv.x * w0 + vv.y * w1 + vv.z * w2 + vv.w * w3;
            }
        }
    }
    if (j < 128) {   // v_l columns
        #pragma unroll
        for (int n = 0; n < NT3; ++n)
            #pragma unroll
            for (int d = 0; d < 3; ++d)
                vl_lds[n][d][j] = acc[n * 3 + d];
    }
    __syncthreads();
    if (j >= 128) {  // v_r columns: v_norm + dot
        int h = j - 128;
        #pragma unroll
        for (int n = 0; n < NT3; ++n) {
            float a0 = acc[n * 3 + 0], a1 = acc[n * 3 + 1], a2 = acc[n * 3 + 2];
            ts_lds[n][128 + h] = sqrtf(a0 * a0 + a1 * a1 + a2 * a2 + NEPS);
            dot_lds[n][h] = a0 * vl_lds[n][0][h] + a1 * vl_lds[n][1][h] + a2 * vl_lds[n][2][h];
        }
    }
    __syncthreads();

    // MLP phase 1: h1 = silu(ts @ Wm1 + bm1)
    int jj = t & 127, g = t >> 7;      // g selects node half (6 nodes each)
    float hacc[6];
    #pragma unroll
    for (int n2 = 0; n2 < 6; ++n2) hacc[n2] = bm1[jj];
    for (int k = 0; k < 256; k += 4) {
        float w0 = Wm1[(k + 0) * H + jj];
        float w1 = Wm1[(k + 1) * H + jj];
        float w2 = Wm1[(k + 2) * H + jj];
        float w3 = Wm1[(k + 3) * H + jj];
        #pragma unroll
        for (int n2 = 0; n2 < 6; ++n2) {
            float4 tv = *reinterpret_cast<const float4*>(&ts_lds[g * 6 + n2][k]);
            hacc[n2] += tv.x * w0 + tv.y * w1 + tv.z * w2 + tv.w * w3;
        }
    }
    __syncthreads();   // all reads of v_norm half done before overwrite
    #pragma unroll
    for (int n2 = 0; n2 < 6; ++n2) ts_lds[g * 6 + n2][128 + jj] = silu_f(hacc[n2]);
    __syncthreads();

    // MLP phase 2 + combine
    float o0[6], o1[6], o2[6];
    #pragma unroll
    for (int n2 = 0; n2 < 6; ++n2) {
        o0[n2] = bm2[jj]; o1[n2] = bm2[128 + jj]; o2[n2] = bm2[256 + jj];
    }
    for (int k = 0; k < H; k += 4) {
        #pragma unroll
        for (int kk = 0; kk < 4; ++kk) {
            float wa = Wm2[(k + kk) * 384 + jj];
            float wb = Wm2[(k + kk) * 384 + 128 + jj];
            float wc = Wm2[(k + kk) * 384 + 256 + jj];
            #pragma unroll
            for (int n2 = 0; n2 < 6; ++n2) {
                float hv = ts_lds[g * 6 + n2][128 + k + kk];
                o0[n2] += hv * wa; o1[n2] += hv * wb; o2[n2] += hv * wc;
            }
        }
    }
    #pragma unroll
    for (int n2 = 0; n2 < 6; ++n2) {
        int n = g * 6 + n2;
        int node = node0 + n;
        if (node < n_nodes) {
            float s_mid = ts_lds[n][jj];
            float ds_u = o0[n2];
            float dvs  = o1[n2];
            float dsv  = o2[n2] * dot_lds[n][jj];
            out[(size_t)node * 512 + jj] = (s_mid + ds_u + dsv) * EPSILON;
            #pragma unroll
            for (int d = 0; d < 3; ++d)
                out[(size_t)node * 512 + 128 + d * 128 + jj] =
                    (v_lds[n][d][jj] + vl_lds[n][d][jj] * dvs) * EPSILON;
        }
    }
}

extern "C" void kernel_launch(void* const* d_in, const int* in_sizes, int n_in,
                              void* d_out, int out_size, void* d_ws, size_t ws_size,
                              hipStream_t stream) {
    const float* s       = (const float*)d_in[0];
    const float* v       = (const float*)d_in[1];
    const float* dir     = (const float*)d_in[2];
    const float* Wij     = (const float*)d_in[3];
    const int*   senders = (const int*)d_in[4];
    const int*   recv    = (const int*)d_in[5];
    const float* Wi1     = (const float*)d_in[6];
    const float* bi1     = (const float*)d_in[7];
    const float* Wi2     = (const float*)d_in[8];
    const float* bi2     = (const float*)d_in[9];
    const float* Wm1     = (const float*)d_in[10];
    const float* bm1     = (const float*)d_in[11];
    const float* Wm2     = (const float*)d_in[12];
    const float* bm2     = (const float*)d_in[13];
    const float* Wvm     = (const float*)d_in[14];

    int n_nodes = in_sizes[0] / H;
    int n_edges = in_sizes[4];
    float* out = (float*)d_out;
    float* x   = (float*)d_ws;   // N*384 floats = 76.8 MB scratch

    k0_init<<<(n_nodes * 128 + 255) / 256, 256, 0, stream>>>(
        (const float4*)s, (const float4*)v, (float4*)out, n_nodes);

    k1_mlp_x<<<(n_nodes + 31) / 32, 128, 0, stream>>>(
        s, Wi1, bi1, Wi2, bi2, x, n_nodes);

    k2_edges<<<(n_edges + 1) / 2, 256, 0, stream>>>(
        x, v, dir, Wij, senders, recv, out, n_edges);

    k3_update<<<(n_nodes + NT3 - 1) / NT3, 256, 0, stream>>>(
        Wvm, Wm1, bm1, Wm2, bm2, out, n_nodes);
}

// Round 2
// 1512.248 us; speedup vs baseline: 1.2756x; 1.2756x over previous
//
#include <hip/hip_runtime.h>

#define H 128
#define EPSILON 0.7071067811865476f
#define NEPS 1e-8f
#define NT3 12

__device__ __forceinline__ float silu_f(float x) {
    return x / (1.0f + __expf(-x));
}

// ---------------- K0 (fallback only): init out = [s | v] ----------------
__global__ void k0_init(const float4* __restrict__ s, const float4* __restrict__ v,
                        float4* __restrict__ out, int n_nodes) {
    int i = blockIdx.x * blockDim.x + threadIdx.x;
    int total = n_nodes * 128;
    if (i >= total) return;
    int n = i >> 7, r = i & 127;
    float4 val;
    if (r < 32) val = s[n * 32 + r];
    else        val = v[n * 96 + (r - 32)];
    out[i] = val;
}

// ---------------- K1: x = silu(s@Wi1 + bi1) @ Wi2 + bi2 ----------------
__global__ __launch_bounds__(128) void k1_mlp_x(
        const float* __restrict__ s,
        const float* __restrict__ Wi1, const float* __restrict__ bi1,
        const float* __restrict__ Wi2, const float* __restrict__ bi2,
        float* __restrict__ x, int n_nodes) {
    __shared__ float s_lds[32][H];
    __shared__ float h_lds[32][H];
    int j = threadIdx.x;
    int node0 = blockIdx.x * 32;

    #pragma unroll
    for (int n = 0; n < 32; ++n) {
        int node = node0 + n; if (node >= n_nodes) node = n_nodes - 1;
        s_lds[n][j] = s[(size_t)node * H + j];
    }
    __syncthreads();

    float acc[32];
    #pragma unroll
    for (int n = 0; n < 32; ++n) acc[n] = bi1[j];
    for (int k = 0; k < H; k += 4) {
        float w0 = Wi1[(k + 0) * H + j];
        float w1 = Wi1[(k + 1) * H + j];
        float w2 = Wi1[(k + 2) * H + j];
        float w3 = Wi1[(k + 3) * H + j];
        #pragma unroll
        for (int n = 0; n < 32; ++n) {
            float4 sv = *reinterpret_cast<const float4*>(&s_lds[n][k]);
            acc[n] += sv.x * w0 + sv.y * w1 + sv.z * w2 + sv.w * w3;
        }
    }
    #pragma unroll
    for (int n = 0; n < 32; ++n) h_lds[n][j] = silu_f(acc[n]);
    __syncthreads();

    for (int c = 0; c < 3; ++c) {
        int col = c * H + j;
        float a2[32];
        #pragma unroll
        for (int n = 0; n < 32; ++n) a2[n] = bi2[col];
        for (int k = 0; k < H; k += 4) {
            float w0 = Wi2[(k + 0) * 384 + col];
            float w1 = Wi2[(k + 1) * 384 + col];
            float w2 = Wi2[(k + 2) * 384 + col];
            float w3 = Wi2[(k + 3) * 384 + col];
            #pragma unroll
            for (int n = 0; n < 32; ++n) {
                float4 hv = *reinterpret_cast<const float4*>(&h_lds[n][k]);
                a2[n] += hv.x * w0 + hv.y * w1 + hv.z * w2 + hv.w * w3;
            }
        }
        #pragma unroll
        for (int n = 0; n < 32; ++n) {
            int node = node0 + n;
            if (node < n_nodes) x[(size_t)node * 384 + col] = a2[n];
        }
    }
}

// ---------------- CSR build ----------------
__global__ void k_hist(const int* __restrict__ senders, int* __restrict__ counts, int n_edges) {
    int e = blockIdx.x * blockDim.x + threadIdx.x;
    if (e < n_edges) atomicAdd(&counts[senders[e]], 1);
}

__global__ __launch_bounds__(1024) void k_scan(
        int* __restrict__ counts_head,   // in: counts, out: running cursor (= starts)
        int* __restrict__ starts, int n) {
    __shared__ int lds[1024];
    __shared__ int s_running;
    int tid = threadIdx.x;
    if (tid == 0) s_running = 0;
    __syncthreads();
    for (int base = 0; base < n; base += 1024) {
        int i = base + tid;
        int c = (i < n) ? counts_head[i] : 0;
        lds[tid] = c;
        __syncthreads();
        for (int off = 1; off < 1024; off <<= 1) {
            int val = (tid >= off) ? lds[tid - off] : 0;
            __syncthreads();
            lds[tid] += val;
            __syncthreads();
        }
        int incl = lds[tid];
        int run = s_running;
        __syncthreads();
        if (i < n) { int sv = run + incl - c; starts[i] = sv; counts_head[i] = sv; }
        if (tid == 1023) s_running = run + incl;
        __syncthreads();
    }
    if (tid == 0) starts[n] = s_running;
}

__global__ void k_scatter(const int* __restrict__ senders, int* __restrict__ head,
                          int* __restrict__ eord, int n_edges) {
    int e = blockIdx.x * blockDim.x + threadIdx.x;
    if (e < n_edges) {
        int p = atomicAdd(&head[senders[e]], 1);
        eord[p] = e;
    }
}

// ---------------- K2 (CSR): per-node gather-accumulate, atomic-free ----------------
__global__ __launch_bounds__(256) void k2_csr(
        const float* __restrict__ s, const float* __restrict__ v,
        const float* __restrict__ x, const float* __restrict__ dir,
        const float* __restrict__ Wij, const int* __restrict__ receivers,
        const int* __restrict__ starts, const int* __restrict__ eord,
        float* __restrict__ out, int n_nodes) {
    __shared__ float red[512];
    int node = blockIdx.x;
    int slot = threadIdx.x >> 7;   // 0 or 1: two edge lanes
    int h = threadIdx.x & 127;
    int beg = starts[node], end = starts[node + 1];
    float ds = 0.f, dv0 = 0.f, dv1 = 0.f, dv2 = 0.f;
    for (int q = beg + slot; q < end; q += 2) {
        int e = eord[q];
        int r = receivers[e];
        const float* we = Wij + (size_t)e * 384;
        const float* xr = x   + (size_t)r * 384;
        const float* vr = v   + (size_t)r * 384;
        float a = we[h]       * xr[h];
        float b = we[128 + h] * xr[128 + h];
        float c = we[256 + h] * xr[256 + h];
        float d0 = dir[(size_t)e * 3 + 0];
        float d1 = dir[(size_t)e * 3 + 1];
        float d2 = dir[(size_t)e * 3 + 2];
        ds  += a;
        dv0 += b * d0 + c * vr[h];
        dv1 += b * d1 + c * vr[128 + h];
        dv2 += b * d2 + c * vr[256 + h];
    }
    if (slot == 1) {
        red[h] = ds; red[128 + h] = dv0; red[256 + h] = dv1; red[384 + h] = dv2;
    }
    __syncthreads();
    if (slot == 0) {
        ds  += red[h];       dv0 += red[128 + h];
        dv1 += red[256 + h]; dv2 += red[384 + h];
        size_t ob = (size_t)node * 512;
        const float* vn = v + (size_t)node * 384;
        out[ob + h]       = (s[(size_t)node * 128 + h] + ds)  * EPSILON;
        out[ob + 128 + h] = (vn[h]       + dv0) * EPSILON;
        out[ob + 256 + h] = (vn[128 + h] + dv1) * EPSILON;
        out[ob + 384 + h] = (vn[256 + h] + dv2) * EPSILON;
    }
}

// ---------------- K2 fallback: atomic scatter ----------------
__global__ __launch_bounds__(256) void k2_edges(
        const float* __restrict__ x, const float* __restrict__ v,
        const float* __restrict__ dir, const float* __restrict__ Wij,
        const int* __restrict__ senders, const int* __restrict__ receivers,
        float* __restrict__ out, int n_edges) {
    int e = blockIdx.x * 2 + (threadIdx.x >> 7);
    int h = threadIdx.x & 127;
    if (e >= n_edges) return;
    int r   = receivers[e];
    int snd = senders[e];
    const float* xr = x   + (size_t)r * 384;
    const float* we = Wij + (size_t)e * 384;
    float ds  = we[h]       * xr[h];
    float dv1 = we[128 + h] * xr[128 + h];
    float dv2 = we[256 + h] * xr[256 + h];
    float d0 = dir[(size_t)e * 3 + 0];
    float d1 = dir[(size_t)e * 3 + 1];
    float d2 = dir[(size_t)e * 3 + 2];
    const float* vr = v + (size_t)r * 384;
    float* o = out + (size_t)snd * 512;
    unsafeAtomicAdd(&o[h],       ds);
    unsafeAtomicAdd(&o[128 + h], dv1 * d0 + dv2 * vr[h]);
    unsafeAtomicAdd(&o[256 + h], dv1 * d1 + dv2 * vr[128 + h]);
    unsafeAtomicAdd(&o[384 + h], dv1 * d2 + dv2 * vr[256 + h]);
}

// ---------------- K3: per-node update ----------------
__global__ __launch_bounds__(256) void k3_update(
        const float* __restrict__ Wvm,
        const float* __restrict__ Wm1, const float* __restrict__ bm1,
        const float* __restrict__ Wm2, const float* __restrict__ bm2,
        float* __restrict__ out, int n_nodes, float premul) {
    __shared__ float v_lds[NT3][3][H];
    __shared__ float vl_lds[NT3][3][H];
    __shared__ float ts_lds[NT3][2 * H];
    __shared__ float dot_lds[NT3][H];
    int t = threadIdx.x;
    int node0 = blockIdx.x * NT3;

    for (int idx = t; idx < NT3 * 512; idx += 256) {
        int n = idx >> 9, r = idx & 511;
        int node = node0 + n; if (node >= n_nodes) node = n_nodes - 1;
        float val = out[(size_t)node * 512 + r] * premul;
        if (r < 128) ts_lds[n][r] = val;
        else         v_lds[n][(r >> 7) - 1][r & 127] = val;
    }
    __syncthreads();

    float acc[NT3 * 3];
    #pragma unroll
    for (int i = 0; i < NT3 * 3; ++i) acc[i] = 0.f;
    int j = t;
    for (int k = 0; k < H; k += 4) {
        float w0 = Wvm[(k + 0) * 256 + j];
        float w1 = Wvm[(k + 1) * 256 + j];
        float w2 = Wvm[(k + 2) * 256 + j];
        float w3 = Wvm[(k + 3) * 256 + j];
        #pragma unroll
        for (int n = 0; n < NT3; ++n) {
            #pragma unroll
            for (int d = 0; d < 3; ++d) {
                float4 vv = *reinterpret_cast<const float4*>(&v_lds[n][d][k]);
                acc[n * 3 + d] += vv.x * w0 + vv.y * w1 + vv.z * w2 + vv.w * w3;
            }
        }
    }
    if (j < 128) {
        #pragma unroll
        for (int n = 0; n < NT3; ++n)
            #pragma unroll
            for (int d = 0; d < 3; ++d)
                vl_lds[n][d][j] = acc[n * 3 + d];
    }
    __syncthreads();
    if (j >= 128) {
        int h = j - 128;
        #pragma unroll
        for (int n = 0; n < NT3; ++n) {
            float a0 = acc[n * 3 + 0], a1 = acc[n * 3 + 1], a2 = acc[n * 3 + 2];
            ts_lds[n][128 + h] = sqrtf(a0 * a0 + a1 * a1 + a2 * a2 + NEPS);
            dot_lds[n][h] = a0 * vl_lds[n][0][h] + a1 * vl_lds[n][1][h] + a2 * vl_lds[n][2][h];
        }
    }
    __syncthreads();

    int jj = t & 127, g = t >> 7;
    float hacc[6];
    #pragma unroll
    for (int n2 = 0; n2 < 6; ++n2) hacc[n2] = bm1[jj];
    for (int k = 0; k < 256; k += 4) {
        float w0 = Wm1[(k + 0) * H + jj];
        float w1 = Wm1[(k + 1) * H + jj];
        float w2 = Wm1[(k + 2) * H + jj];
        float w3 = Wm1[(k + 3) * H + jj];
        #pragma unroll
        for (int n2 = 0; n2 < 6; ++n2) {
            float4 tv = *reinterpret_cast<const float4*>(&ts_lds[g * 6 + n2][k]);
            hacc[n2] += tv.x * w0 + tv.y * w1 + tv.z * w2 + tv.w * w3;
        }
    }
    __syncthreads();
    #pragma unroll
    for (int n2 = 0; n2 < 6; ++n2) ts_lds[g * 6 + n2][128 + jj] = silu_f(hacc[n2]);
    __syncthreads();

    float o0[6], o1[6], o2[6];
    #pragma unroll
    for (int n2 = 0; n2 < 6; ++n2) {
        o0[n2] = bm2[jj]; o1[n2] = bm2[128 + jj]; o2[n2] = bm2[256 + jj];
    }
    for (int k = 0; k < H; k += 4) {
        #pragma unroll
        for (int kk = 0; kk < 4; ++kk) {
            float wa = Wm2[(k + kk) * 384 + jj];
            float wb = Wm2[(k + kk) * 384 + 128 + jj];
            float wc = Wm2[(k + kk) * 384 + 256 + jj];
            #pragma unroll
            for (int n2 = 0; n2 < 6; ++n2) {
                float hv = ts_lds[g * 6 + n2][128 + k + kk];
                o0[n2] += hv * wa; o1[n2] += hv * wb; o2[n2] += hv * wc;
            }
        }
    }
    #pragma unroll
    for (int n2 = 0; n2 < 6; ++n2) {
        int n = g * 6 + n2;
        int node = node0 + n;
        if (node < n_nodes) {
            float s_mid = ts_lds[n][jj];
            float ds_u = o0[n2];
            float dvs  = o1[n2];
            float dsv  = o2[n2] * dot_lds[n][jj];
            out[(size_t)node * 512 + jj] = (s_mid + ds_u + dsv) * EPSILON;
            #pragma unroll
            for (int d = 0; d < 3; ++d)
                out[(size_t)node * 512 + 128 + d * 128 + jj] =
                    (v_lds[n][d][jj] + vl_lds[n][d][jj] * dvs) * EPSILON;
        }
    }
}

static inline size_t align_up(size_t x, size_t a) { return (x + a - 1) / a * a; }

extern "C" void kernel_launch(void* const* d_in, const int* in_sizes, int n_in,
                              void* d_out, int out_size, void* d_ws, size_t ws_size,
                              hipStream_t stream) {
    const float* s       = (const float*)d_in[0];
    const float* v       = (const float*)d_in[1];
    const float* dir     = (const float*)d_in[2];
    const float* Wij     = (const float*)d_in[3];
    const int*   senders = (const int*)d_in[4];
    const int*   recv    = (const int*)d_in[5];
    const float* Wi1     = (const float*)d_in[6];
    const float* bi1     = (const float*)d_in[7];
    const float* Wi2     = (const float*)d_in[8];
    const float* bi2     = (const float*)d_in[9];
    const float* Wm1     = (const float*)d_in[10];
    const float* bm1     = (const float*)d_in[11];
    const float* Wm2     = (const float*)d_in[12];
    const float* bm2     = (const float*)d_in[13];
    const float* Wvm     = (const float*)d_in[14];

    int n_nodes = in_sizes[0] / H;
    int n_edges = in_sizes[4];
    float* out = (float*)d_out;

    // workspace layout
    char* ws = (char*)d_ws;
    size_t off = 0;
    float* x      = (float*)(ws + off); off = align_up(off + (size_t)n_nodes * 384 * 4, 256);
    int*   starts = (int*)(ws + off);   off = align_up(off + (size_t)(n_nodes + 1) * 4, 256);
    int*   head   = (int*)(ws + off);   off = align_up(off + (size_t)n_nodes * 4, 256);
    int*   eord   = (int*)(ws + off);   off = align_up(off + (size_t)n_edges * 4, 256);
    bool csr_ok = (off <= ws_size);

    k1_mlp_x<<<(n_nodes + 31) / 32, 128, 0, stream>>>(
        s, Wi1, bi1, Wi2, bi2, x, n_nodes);

    if (csr_ok) {
        hipMemsetAsync(head, 0, (size_t)n_nodes * 4, stream);
        k_hist<<<(n_edges + 255) / 256, 256, 0, stream>>>(senders, head, n_edges);
        k_scan<<<1, 1024, 0, stream>>>(head, starts, n_nodes);
        k_scatter<<<(n_edges + 255) / 256, 256, 0, stream>>>(senders, head, eord, n_edges);
        k2_csr<<<n_nodes, 256, 0, stream>>>(
            s, v, x, dir, Wij, recv, starts, eord, out, n_nodes);
        k3_update<<<(n_nodes + NT3 - 1) / NT3, 256, 0, stream>>>(
            Wvm, Wm1, bm1, Wm2, bm2, out, n_nodes, 1.0f);
    } else {
        k0_init<<<(n_nodes * 128 + 255) / 256, 256, 0, stream>>>(
            (const float4*)s, (const float4*)v, (float4*)out, n_nodes);
        k2_edges<<<(n_edges + 1) / 2, 256, 0, stream>>>(
            x, v, dir, Wij, senders, recv, out, n_edges);
        k3_update<<<(n_nodes + NT3 - 1) / NT3, 256, 0, stream>>>(
            Wvm, Wm1, bm1, Wm2, bm2, out, n_nodes, EPSILON);
    }
}

// Round 3
// 852.784 us; speedup vs baseline: 2.2620x; 1.7733x over previous
//
#include <hip/hip_runtime.h>

#define H 128
#define EPSILON 0.7071067811865476f
#define NEPS 1e-8f
#define NT3 12

typedef short bf16x8 __attribute__((ext_vector_type(8)));
typedef float f32x4 __attribute__((ext_vector_type(4)));

__device__ __forceinline__ float silu_f(float x) {
    return x / (1.0f + __expf(-x));
}

// split f32 into bf16 hi + bf16 lo (RNE)
__device__ __forceinline__ void split_bf(float w, unsigned short& h, unsigned short& l) {
    unsigned ub = __float_as_uint(w);
    unsigned h16 = (ub + 0x7FFF + ((ub >> 16) & 1)) >> 16;
    float hf = __uint_as_float(h16 << 16);
    float r = w - hf;
    unsigned ur = __float_as_uint(r);
    unsigned l16 = (ur + 0x7FFF + ((ur >> 16) & 1)) >> 16;
    h = (unsigned short)h16; l = (unsigned short)l16;
}
__device__ __forceinline__ float bfu(unsigned short u) { return __uint_as_float(((unsigned)u) << 16); }

__device__ __forceinline__ f32x4 mfma3(bf16x8 ah, bf16x8 al, bf16x8 bh, bf16x8 bl, f32x4 acc) {
    acc = __builtin_amdgcn_mfma_f32_16x16x32_bf16(ah, bh, acc, 0, 0, 0);
    acc = __builtin_amdgcn_mfma_f32_16x16x32_bf16(al, bh, acc, 0, 0, 0);
    acc = __builtin_amdgcn_mfma_f32_16x16x32_bf16(ah, bl, acc, 0, 0, 0);
    return acc;
}

// ---------------- pack weights K x N -> fragment-major bf16 hi/lo ----------------
// layout: elem (ks, ct, lane, j) at ((ks*CT+ct)*64+lane)*8+j  = W[ks*32+(lane>>4)*8+j][ct*16+(lane&15)]
__global__ void k_pack(const float* __restrict__ W, int K, int N,
                       unsigned short* __restrict__ hi, unsigned short* __restrict__ lo) {
    int tid = blockIdx.x * blockDim.x + threadIdx.x;
    int total = K * N;
    if (tid >= total) return;
    int CT = N >> 4;
    int j = tid & 7;
    int l = (tid >> 3) & 63;
    int rest = tid >> 9;
    int ct = rest % CT;
    int ks = rest / CT;
    int row = ks * 32 + ((l >> 4) << 3) + j;
    int col = ct * 16 + (l & 15);
    float w = W[(size_t)row * N + col];
    unsigned short h16, l16;
    split_bf(w, h16, l16);
    hi[tid] = h16; lo[tid] = l16;
}

// ---------------- K1 (MFMA): x = silu(s@Wi1+bi1)@Wi2+bi2, 16 nodes/block ----------------
__global__ __launch_bounds__(256, 4) void k1_mfma(
        const float* __restrict__ s,
        const unsigned short* __restrict__ W1h, const unsigned short* __restrict__ W1l,
        const unsigned short* __restrict__ W2h, const unsigned short* __restrict__ W2l,
        const float* __restrict__ bi1, const float* __restrict__ bi2,
        float* __restrict__ x, int n_nodes) {
    __shared__ unsigned short Ahi[16 * 136], Alo[16 * 136];
    __shared__ unsigned short Hhi[16 * 136], Hlo[16 * 136];
    int t = threadIdx.x;
    int node0 = blockIdx.x * 16;
    int wv = t >> 6, lane = t & 63;
    int g = lane >> 4, cl = lane & 15;

    // stage s -> bf16 hi/lo
    #pragma unroll
    for (int i = 0; i < 8; ++i) {
        int flat = t + i * 256;
        int n = flat >> 7, k = flat & 127;
        int node = node0 + n; if (node >= n_nodes) node = n_nodes - 1;
        unsigned short h16, l16;
        split_bf(s[(size_t)node * 128 + k], h16, l16);
        Ahi[n * 136 + k] = h16; Alo[n * 136 + k] = l16;
    }
    __syncthreads();

    // GEMM A: (16x128)@(128x128), 8 col-tiles, wave -> 2
    f32x4 acc1[2] = {};
    #pragma unroll
    for (int ks = 0; ks < 4; ++ks) {
        bf16x8 ah = *(const bf16x8*)&Ahi[cl * 136 + ks * 32 + g * 8];
        bf16x8 al = *(const bf16x8*)&Alo[cl * 136 + ks * 32 + g * 8];
        #pragma unroll
        for (int c = 0; c < 2; ++c) {
            int ct = wv * 2 + c;
            bf16x8 bh = *(const bf16x8*)&W1h[((size_t)(ks * 8 + ct) * 64 + lane) * 8];
            bf16x8 bl = *(const bf16x8*)&W1l[((size_t)(ks * 8 + ct) * 64 + lane) * 8];
            acc1[c] = mfma3(ah, al, bh, bl, acc1[c]);
        }
    }
    #pragma unroll
    for (int c = 0; c < 2; ++c) {
        int col = (wv * 2 + c) * 16 + cl;
        float bias = bi1[col];
        #pragma unroll
        for (int r = 0; r < 4; ++r) {
            float hval = silu_f(acc1[c][r] + bias);
            unsigned short h16, l16; split_bf(hval, h16, l16);
            int row = g * 4 + r;
            Hhi[row * 136 + col] = h16; Hlo[row * 136 + col] = l16;
        }
    }
    __syncthreads();

    // GEMM B: (16x128)@(128x384), 24 col-tiles, wave -> 6
    f32x4 acc2[6] = {};
    #pragma unroll
    for (int ks = 0; ks < 4; ++ks) {
        bf16x8 ah = *(const bf16x8*)&Hhi[cl * 136 + ks * 32 + g * 8];
        bf16x8 al = *(const bf16x8*)&Hlo[cl * 136 + ks * 32 + g * 8];
        #pragma unroll
        for (int c = 0; c < 6; ++c) {
            int ct = wv * 6 + c;
            bf16x8 bh = *(const bf16x8*)&W2h[((size_t)(ks * 24 + ct) * 64 + lane) * 8];
            bf16x8 bl = *(const bf16x8*)&W2l[((size_t)(ks * 24 + ct) * 64 + lane) * 8];
            acc2[c] = mfma3(ah, al, bh, bl, acc2[c]);
        }
    }
    #pragma unroll
    for (int c = 0; c < 6; ++c) {
        int col = (wv * 6 + c) * 16 + cl;
        float bias = bi2[col];
        #pragma unroll
        for (int r = 0; r < 4; ++r) {
            int node = node0 + g * 4 + r;
            if (node < n_nodes) x[(size_t)node * 384 + col] = acc2[c][r] + bias;
        }
    }
}

// ---------------- CSR build ----------------
__global__ void k_hist(const int* __restrict__ senders, int* __restrict__ counts, int n_edges) {
    int e = blockIdx.x * blockDim.x + threadIdx.x;
    if (e < n_edges) atomicAdd(&counts[senders[e]], 1);
}

__global__ __launch_bounds__(1024) void k_scan(
        int* __restrict__ counts_head, int* __restrict__ starts, int n) {
    __shared__ int lds[1024];
    __shared__ int s_running;
    int tid = threadIdx.x;
    if (tid == 0) s_running = 0;
    __syncthreads();
    for (int base = 0; base < n; base += 1024) {
        int i = base + tid;
        int c = (i < n) ? counts_head[i] : 0;
        lds[tid] = c;
        __syncthreads();
        for (int off = 1; off < 1024; off <<= 1) {
            int val = (tid >= off) ? lds[tid - off] : 0;
            __syncthreads();
            lds[tid] += val;
            __syncthreads();
        }
        int incl = lds[tid];
        int run = s_running;
        __syncthreads();
        if (i < n) { int sv = run + incl - c; starts[i] = sv; counts_head[i] = sv; }
        if (tid == 1023) s_running = run + incl;
        __syncthreads();
    }
    if (tid == 0) starts[n] = s_running;
}

__global__ void k_scatter(const int* __restrict__ senders, int* __restrict__ head,
                          int* __restrict__ eord, int n_edges) {
    int e = blockIdx.x * blockDim.x + threadIdx.x;
    if (e < n_edges) {
        int p = atomicAdd(&head[senders[e]], 1);
        eord[p] = e;
    }
}

// ---------------- K2 (CSR): per-node gather-accumulate ----------------
__global__ __launch_bounds__(256) void k2_csr(
        const float* __restrict__ s, const float* __restrict__ v,
        const float* __restrict__ x, const float* __restrict__ dir,
        const float* __restrict__ Wij, const int* __restrict__ receivers,
        const int* __restrict__ starts, const int* __restrict__ eord,
        float* __restrict__ out, int n_nodes) {
    __shared__ float red[512];
    int node = blockIdx.x;
    int slot = threadIdx.x >> 7;
    int h = threadIdx.x & 127;
    int beg = starts[node], end = starts[node + 1];
    float ds = 0.f, dv0 = 0.f, dv1 = 0.f, dv2 = 0.f;
    for (int q = beg + slot; q < end; q += 2) {
        int e = eord[q];
        int r = receivers[e];
        const float* we = Wij + (size_t)e * 384;
        const float* xr = x   + (size_t)r * 384;
        const float* vr = v   + (size_t)r * 384;
        float a = we[h]       * xr[h];
        float b = we[128 + h] * xr[128 + h];
        float c = we[256 + h] * xr[256 + h];
        float d0 = dir[(size_t)e * 3 + 0];
        float d1 = dir[(size_t)e * 3 + 1];
        float d2 = dir[(size_t)e * 3 + 2];
        ds  += a;
        dv0 += b * d0 + c * vr[h];
        dv1 += b * d1 + c * vr[128 + h];
        dv2 += b * d2 + c * vr[256 + h];
    }
    if (slot == 1) {
        red[h] = ds; red[128 + h] = dv0; red[256 + h] = dv1; red[384 + h] = dv2;
    }
    __syncthreads();
    if (slot == 0) {
        ds  += red[h];       dv0 += red[128 + h];
        dv1 += red[256 + h]; dv2 += red[384 + h];
        size_t ob = (size_t)node * 512;
        const float* vn = v + (size_t)node * 384;
        out[ob + h]       = (s[(size_t)node * 128 + h] + ds)  * EPSILON;
        out[ob + 128 + h] = (vn[h]       + dv0) * EPSILON;
        out[ob + 256 + h] = (vn[128 + h] + dv1) * EPSILON;
        out[ob + 384 + h] = (vn[256 + h] + dv2) * EPSILON;
    }
}

// ---------------- K3 (MFMA): fused update, 16 nodes/block ----------------
__global__ __launch_bounds__(256, 1) void k3_mfma(
        const unsigned short* __restrict__ Wvh, const unsigned short* __restrict__ Wvl,
        const unsigned short* __restrict__ W1h, const unsigned short* __restrict__ W1l,
        const unsigned short* __restrict__ W2h, const unsigned short* __restrict__ W2l,
        const float* __restrict__ bm1, const float* __restrict__ bm2,
        float* __restrict__ out, int n_nodes) {
    __shared__ float vlb[48 * 132];          // v_l f32
    __shared__ float vrc[48 * 132];          // v_r f32, later C3 [16][396]
    __shared__ unsigned short Ahi[48 * 136], Alo[48 * 136];   // v_mid bf16 hi/lo
    __shared__ unsigned short Thi[16 * 264], Tlo[16 * 264];   // ts
    __shared__ unsigned short Hhi[16 * 136], Hlo[16 * 136];   // h1
    __shared__ float smid[16 * 128];
    __shared__ float dotb[16 * 128];

    int t = threadIdx.x;
    int node0 = blockIdx.x * 16;
    int wv = t >> 6, lane = t & 63;
    int g = lane >> 4, cl = lane & 15;

    // ---- phase 0: stage v_mid (48x128) and s_mid (16x128) ----
    #pragma unroll
    for (int i = 0; i < 24; ++i) {
        int flat = t + i * 256;
        int row = flat >> 7, k = flat & 127;      // row = n*3+d
        int n = row / 3, d = row - n * 3;
        int node = node0 + n; if (node >= n_nodes) node = n_nodes - 1;
        float val = out[(size_t)node * 512 + 128 + d * 128 + k];
        unsigned short h16, l16; split_bf(val, h16, l16);
        Ahi[row * 136 + k] = h16; Alo[row * 136 + k] = l16;
    }
    #pragma unroll
    for (int i = 0; i < 8; ++i) {
        int flat = t + i * 256;
        int n = flat >> 7, k = flat & 127;
        int node = node0 + n; if (node >= n_nodes) node = n_nodes - 1;
        smid[n * 128 + k] = out[(size_t)node * 512 + k];
    }
    __syncthreads();

    // ---- GEMM1: (48x128)@(128x256) -> vl | vr ----
    #pragma unroll
    for (int rt = 0; rt < 3; ++rt) {
        bf16x8 ah[4], al[4];
        #pragma unroll
        for (int ks = 0; ks < 4; ++ks) {
            ah[ks] = *(const bf16x8*)&Ahi[(rt * 16 + cl) * 136 + ks * 32 + g * 8];
            al[ks] = *(const bf16x8*)&Alo[(rt * 16 + cl) * 136 + ks * 32 + g * 8];
        }
        f32x4 acc[4] = {};
        #pragma unroll
        for (int ks = 0; ks < 4; ++ks) {
            #pragma unroll
            for (int c = 0; c < 4; ++c) {
                int ct = wv * 4 + c;
                bf16x8 bh = *(const bf16x8*)&Wvh[((size_t)(ks * 16 + ct) * 64 + lane) * 8];
                bf16x8 bl = *(const bf16x8*)&Wvl[((size_t)(ks * 16 + ct) * 64 + lane) * 8];
                acc[c] = mfma3(ah[ks], al[ks], bh, bl, acc[c]);
            }
        }
        #pragma unroll
        for (int c = 0; c < 4; ++c) {
            int col = (wv * 4 + c) * 16 + cl;
            float* dst = (col < 128) ? vlb : vrc;
            int cc = col & 127;
            #pragma unroll
            for (int r = 0; r < 4; ++r)
                dst[(rt * 16 + g * 4 + r) * 132 + cc] = acc[c][r];
        }
    }
    __syncthreads();

    // ---- phase 2: v_norm, dot, build ts ----
    #pragma unroll
    for (int i = 0; i < 8; ++i) {
        int flat = t + i * 256;
        int n = flat >> 7, h = flat & 127;
        float r0 = vrc[(3 * n + 0) * 132 + h];
        float r1 = vrc[(3 * n + 1) * 132 + h];
        float r2 = vrc[(3 * n + 2) * 132 + h];
        float l0 = vlb[(3 * n + 0) * 132 + h];
        float l1 = vlb[(3 * n + 1) * 132 + h];
        float l2 = vlb[(3 * n + 2) * 132 + h];
        float nrm = sqrtf(r0 * r0 + r1 * r1 + r2 * r2 + NEPS);
        dotb[n * 128 + h] = r0 * l0 + r1 * l1 + r2 * l2;
        unsigned short h16, l16;
        split_bf(nrm, h16, l16);
        Thi[n * 264 + 128 + h] = h16; Tlo[n * 264 + 128 + h] = l16;
        split_bf(smid[n * 128 + h], h16, l16);
        Thi[n * 264 + h] = h16; Tlo[n * 264 + h] = l16;
    }
    __syncthreads();

    // ---- GEMM2: (16x256)@(256x128) + bm1 -> silu -> h1 ----
    f32x4 acc2[2] = {};
    #pragma unroll
    for (int ks = 0; ks < 8; ++ks) {
        bf16x8 ah = *(const bf16x8*)&Thi[cl * 264 + ks * 32 + g * 8];
        bf16x8 al = *(const bf16x8*)&Tlo[cl * 264 + ks * 32 + g * 8];
        #pragma unroll
        for (int c = 0; c < 2; ++c) {
            int ct = wv * 2 + c;
            bf16x8 bh = *(const bf16x8*)&W1h[((size_t)(ks * 8 + ct) * 64 + lane) * 8];
            bf16x8 bl = *(const bf16x8*)&W1l[((size_t)(ks * 8 + ct) * 64 + lane) * 8];
            acc2[c] = mfma3(ah, al, bh, bl, acc2[c]);
        }
    }
    #pragma unroll
    for (int c = 0; c < 2; ++c) {
        int col = (wv * 2 + c) * 16 + cl;
        float bias = bm1[col];
        #pragma unroll
        for (int r = 0; r < 4; ++r) {
            float hval = silu_f(acc2[c][r] + bias);
            unsigned short h16, l16; split_bf(hval, h16, l16);
            int row = g * 4 + r;
            Hhi[row * 136 + col] = h16; Hlo[row * 136 + col] = l16;
        }
    }
    __syncthreads();

    // ---- GEMM3: (16x128)@(128x384) + bm2 -> C3 (in vrc as [16][396]) ----
    f32x4 acc3[6] = {};
    #pragma unroll
    for (int ks = 0; ks < 4; ++ks) {
        bf16x8 ah = *(const bf16x8*)&Hhi[cl * 136 + ks * 32 + g * 8];
        bf16x8 al = *(const bf16x8*)&Hlo[cl * 136 + ks * 32 + g * 8];
        #pragma unroll
        for (int c = 0; c < 6; ++c) {
            int ct = wv * 6 + c;
            bf16x8 bh = *(const bf16x8*)&W2h[((size_t)(ks * 24 + ct) * 64 + lane) * 8];
            bf16x8 bl = *(const bf16x8*)&W2l[((size_t)(ks * 24 + ct) * 64 + lane) * 8];
            acc3[c] = mfma3(ah, al, bh, bl, acc3[c]);
        }
    }
    __syncthreads();   // vr reads (phase 2) complete before overwrite
    #pragma unroll
    for (int c = 0; c < 6; ++c) {
        int col = (wv * 6 + c) * 16 + cl;
        float bias = bm2[col];
        #pragma unroll
        for (int r = 0; r < 4; ++r)
            vrc[(g * 4 + r) * 396 + col] = acc3[c][r] + bias;
    }
    __syncthreads();

    // ---- final combine ----
    #pragma unroll
    for (int i = 0; i < 8; ++i) {
        int flat = t + i * 256;
        int n = flat >> 7, h = flat & 127;
        int node = node0 + n;
        if (node >= n_nodes) continue;
        float ds_u = vrc[n * 396 + h];
        float dv_u = vrc[n * 396 + 128 + h];
        float dsv  = vrc[n * 396 + 256 + h] * dotb[n * 128 + h];
        float s_out = (smid[n * 128 + h] + ds_u + dsv) * EPSILON;
        out[(size_t)node * 512 + h] = s_out;
        #pragma unroll
        for (int d = 0; d < 3; ++d) {
            int row = 3 * n + d;
            float vmid = bfu(Ahi[row * 136 + h]) + bfu(Alo[row * 136 + h]);
            float vl_v = vlb[row * 132 + h];
            out[(size_t)node * 512 + 128 + d * 128 + h] = (vmid + vl_v * dv_u) * EPSILON;
        }
    }
}

// ---------------- fallback kernels (round-1 path) ----------------
__global__ void k0_init(const float4* __restrict__ s, const float4* __restrict__ v,
                        float4* __restrict__ out, int n_nodes) {
    int i = blockIdx.x * blockDim.x + threadIdx.x;
    int total = n_nodes * 128;
    if (i >= total) return;
    int n = i >> 7, r = i & 127;
    float4 val;
    if (r < 32) val = s[n * 32 + r];
    else        val = v[n * 96 + (r - 32)];
    out[i] = val;
}

__global__ __launch_bounds__(128) void k1_mlp_x(
        const float* __restrict__ s,
        const float* __restrict__ Wi1, const float* __restrict__ bi1,
        const float* __restrict__ Wi2, const float* __restrict__ bi2,
        float* __restrict__ x, int n_nodes) {
    __shared__ float s_lds[32][H];
    __shared__ float h_lds[32][H];
    int j = threadIdx.x;
    int node0 = blockIdx.x * 32;
    #pragma unroll
    for (int n = 0; n < 32; ++n) {
        int node = node0 + n; if (node >= n_nodes) node = n_nodes - 1;
        s_lds[n][j] = s[(size_t)node * H + j];
    }
    __syncthreads();
    float acc[32];
    #pragma unroll
    for (int n = 0; n < 32; ++n) acc[n] = bi1[j];
    for (int k = 0; k < H; k += 4) {
        float w0 = Wi1[(k + 0) * H + j];
        float w1 = Wi1[(k + 1) * H + j];
        float w2 = Wi1[(k + 2) * H + j];
        float w3 = Wi1[(k + 3) * H + j];
        #pragma unroll
        for (int n = 0; n < 32; ++n) {
            float4 sv = *reinterpret_cast<const float4*>(&s_lds[n][k]);
            acc[n] += sv.x * w0 + sv.y * w1 + sv.z * w2 + sv.w * w3;
        }
    }
    #pragma unroll
    for (int n = 0; n < 32; ++n) h_lds[n][j] = silu_f(acc[n]);
    __syncthreads();
    for (int c = 0; c < 3; ++c) {
        int col = c * H + j;
        float a2[32];
        #pragma unroll
        for (int n = 0; n < 32; ++n) a2[n] = bi2[col];
        for (int k = 0; k < H; k += 4) {
            float w0 = Wi2[(k + 0) * 384 + col];
            float w1 = Wi2[(k + 1) * 384 + col];
            float w2 = Wi2[(k + 2) * 384 + col];
            float w3 = Wi2[(k + 3) * 384 + col];
            #pragma unroll
            for (int n = 0; n < 32; ++n) {
                float4 hv = *reinterpret_cast<const float4*>(&h_lds[n][k]);
                a2[n] += hv.x * w0 + hv.y * w1 + hv.z * w2 + hv.w * w3;
            }
        }
        #pragma unroll
        for (int n = 0; n < 32; ++n) {
            int node = node0 + n;
            if (node < n_nodes) x[(size_t)node * 384 + col] = a2[n];
        }
    }
}

__global__ __launch_bounds__(256) void k2_edges(
        const float* __restrict__ x, const float* __restrict__ v,
        const float* __restrict__ dir, const float* __restrict__ Wij,
        const int* __restrict__ senders, const int* __restrict__ receivers,
        float* __restrict__ out, int n_edges) {
    int e = blockIdx.x * 2 + (threadIdx.x >> 7);
    int h = threadIdx.x & 127;
    if (e >= n_edges) return;
    int r   = receivers[e];
    int snd = senders[e];
    const float* xr = x   + (size_t)r * 384;
    const float* we = Wij + (size_t)e * 384;
    float ds  = we[h]       * xr[h];
    float dv1 = we[128 + h] * xr[128 + h];
    float dv2 = we[256 + h] * xr[256 + h];
    float d0 = dir[(size_t)e * 3 + 0];
    float d1 = dir[(size_t)e * 3 + 1];
    float d2 = dir[(size_t)e * 3 + 2];
    const float* vr = v + (size_t)r * 384;
    float* o = out + (size_t)snd * 512;
    unsafeAtomicAdd(&o[h],       ds);
    unsafeAtomicAdd(&o[128 + h], dv1 * d0 + dv2 * vr[h]);
    unsafeAtomicAdd(&o[256 + h], dv1 * d1 + dv2 * vr[128 + h]);
    unsafeAtomicAdd(&o[384 + h], dv1 * d2 + dv2 * vr[256 + h]);
}

__global__ __launch_bounds__(256) void k3_update(
        const float* __restrict__ Wvm,
        const float* __restrict__ Wm1, const float* __restrict__ bm1,
        const float* __restrict__ Wm2, const float* __restrict__ bm2,
        float* __restrict__ out, int n_nodes, float premul) {
    __shared__ float v_lds[NT3][3][H];
    __shared__ float vl_lds[NT3][3][H];
    __shared__ float ts_lds[NT3][2 * H];
    __shared__ float dot_lds[NT3][H];
    int t = threadIdx.x;
    int node0 = blockIdx.x * NT3;
    for (int idx = t; idx < NT3 * 512; idx += 256) {
        int n = idx >> 9, r = idx & 511;
        int node = node0 + n; if (node >= n_nodes) node = n_nodes - 1;
        float val = out[(size_t)node * 512 + r] * premul;
        if (r < 128) ts_lds[n][r] = val;
        else         v_lds[n][(r >> 7) - 1][r & 127] = val;
    }
    __syncthreads();
    float acc[NT3 * 3];
    #pragma unroll
    for (int i = 0; i < NT3 * 3; ++i) acc[i] = 0.f;
    int j = t;
    for (int k = 0; k < H; k += 4) {
        float w0 = Wvm[(k + 0) * 256 + j];
        float w1 = Wvm[(k + 1) * 256 + j];
        float w2 = Wvm[(k + 2) * 256 + j];
        float w3 = Wvm[(k + 3) * 256 + j];
        #pragma unroll
        for (int n = 0; n < NT3; ++n) {
            #pragma unroll
            for (int d = 0; d < 3; ++d) {
                float4 vv = *reinterpret_cast<const float4*>(&v_lds[n][d][k]);
                acc[n * 3 + d] += vv.x * w0 + vv.y * w1 + vv.z * w2 + vv.w * w3;
            }
        }
    }
    if (j < 128) {
        #pragma unroll
        for (int n = 0; n < NT3; ++n)
            #pragma unroll
            for (int d = 0; d < 3; ++d)
                vl_lds[n][d][j] = acc[n * 3 + d];
    }
    __syncthreads();
    if (j >= 128) {
        int h = j - 128;
        #pragma unroll
        for (int n = 0; n < NT3; ++n) {
            float a0 = acc[n * 3 + 0], a1 = acc[n * 3 + 1], a2 = acc[n * 3 + 2];
            ts_lds[n][128 + h] = sqrtf(a0 * a0 + a1 * a1 + a2 * a2 + NEPS);
            dot_lds[n][h] = a0 * vl_lds[n][0][h] + a1 * vl_lds[n][1][h] + a2 * vl_lds[n][2][h];
        }
    }
    __syncthreads();
    int jj = t & 127, g = t >> 7;
    float hacc[6];
    #pragma unroll
    for (int n2 = 0; n2 < 6; ++n2) hacc[n2] = bm1[jj];
    for (int k = 0; k < 256; k += 4) {
        float w0 = Wm1[(k + 0) * H + jj];
        float w1 = Wm1[(k + 1) * H + jj];
        float w2 = Wm1[(k + 2) * H + jj];
        float w3 = Wm1[(k + 3) * H + jj];
        #pragma unroll
        for (int n2 = 0; n2 < 6; ++n2) {
            float4 tv = *reinterpret_cast<const float4*>(&ts_lds[g * 6 + n2][k]);
            hacc[n2] += tv.x * w0 + tv.y * w1 + tv.z * w2 + tv.w * w3;
        }
    }
    __syncthreads();
    #pragma unroll
    for (int n2 = 0; n2 < 6; ++n2) ts_lds[g * 6 + n2][128 + jj] = silu_f(hacc[n2]);
    __syncthreads();
    float o0[6], o1[6], o2[6];
    #pragma unroll
    for (int n2 = 0; n2 < 6; ++n2) {
        o0[n2] = bm2[jj]; o1[n2] = bm2[128 + jj]; o2[n2] = bm2[256 + jj];
    }
    for (int k = 0; k < H; k += 4) {
        #pragma unroll
        for (int kk = 0; kk < 4; ++kk) {
            float wa = Wm2[(k + kk) * 384 + jj];
            float wb = Wm2[(k + kk) * 384 + 128 + jj];
            float wc = Wm2[(k + kk) * 384 + 256 + jj];
            #pragma unroll
            for (int n2 = 0; n2 < 6; ++n2) {
                float hv = ts_lds[g * 6 + n2][128 + k + kk];
                o0[n2] += hv * wa; o1[n2] += hv * wb; o2[n2] += hv * wc;
            }
        }
    }
    #pragma unroll
    for (int n2 = 0; n2 < 6; ++n2) {
        int n = g * 6 + n2;
        int node = node0 + n;
        if (node < n_nodes) {
            float s_mid = ts_lds[n][jj];
            float ds_u = o0[n2];
            float dvs  = o1[n2];
            float dsv  = o2[n2] * dot_lds[n][jj];
            out[(size_t)node * 512 + jj] = (s_mid + ds_u + dsv) * EPSILON;
            #pragma unroll
            for (int d = 0; d < 3; ++d)
                out[(size_t)node * 512 + 128 + d * 128 + jj] =
                    (v_lds[n][d][jj] + vl_lds[n][d][jj] * dvs) * EPSILON;
        }
    }
}

static inline size_t align_up(size_t x, size_t a) { return (x + a - 1) / a * a; }

extern "C" void kernel_launch(void* const* d_in, const int* in_sizes, int n_in,
                              void* d_out, int out_size, void* d_ws, size_t ws_size,
                              hipStream_t stream) {
    const float* s       = (const float*)d_in[0];
    const float* v       = (const float*)d_in[1];
    const float* dir     = (const float*)d_in[2];
    const float* Wij     = (const float*)d_in[3];
    const int*   senders = (const int*)d_in[4];
    const int*   recv    = (const int*)d_in[5];
    const float* Wi1     = (const float*)d_in[6];
    const float* bi1     = (const float*)d_in[7];
    const float* Wi2     = (const float*)d_in[8];
    const float* bi2     = (const float*)d_in[9];
    const float* Wm1     = (const float*)d_in[10];
    const float* bm1     = (const float*)d_in[11];
    const float* Wm2     = (const float*)d_in[12];
    const float* bm2     = (const float*)d_in[13];
    const float* Wvm     = (const float*)d_in[14];

    int n_nodes = in_sizes[0] / H;
    int n_edges = in_sizes[4];
    float* out = (float*)d_out;

    // workspace layout
    char* ws = (char*)d_ws;
    size_t off = 0;
    float* x      = (float*)(ws + off); off = align_up(off + (size_t)n_nodes * 384 * 4, 256);
    int*   starts = (int*)(ws + off);   off = align_up(off + (size_t)(n_nodes + 1) * 4, 256);
    int*   head   = (int*)(ws + off);   off = align_up(off + (size_t)n_nodes * 4, 256);
    int*   eord   = (int*)(ws + off);   off = align_up(off + (size_t)n_edges * 4, 256);
    size_t csr_end = off;
    // packed weights (bf16 hi/lo, fragment-major)
    unsigned short* Wi1h = (unsigned short*)(ws + off); off = align_up(off + 16384 * 2, 256);
    unsigned short* Wi1l = (unsigned short*)(ws + off); off = align_up(off + 16384 * 2, 256);
    unsigned short* Wi2h = (unsigned short*)(ws + off); off = align_up(off + 49152 * 2, 256);
    unsigned short* Wi2l = (unsigned short*)(ws + off); off = align_up(off + 49152 * 2, 256);
    unsigned short* Wvh  = (unsigned short*)(ws + off); off = align_up(off + 32768 * 2, 256);
    unsigned short* Wvl  = (unsigned short*)(ws + off); off = align_up(off + 32768 * 2, 256);
    unsigned short* Wm1h = (unsigned short*)(ws + off); off = align_up(off + 32768 * 2, 256);
    unsigned short* Wm1l = (unsigned short*)(ws + off); off = align_up(off + 32768 * 2, 256);
    unsigned short* Wm2h = (unsigned short*)(ws + off); off = align_up(off + 49152 * 2, 256);
    unsigned short* Wm2l = (unsigned short*)(ws + off); off = align_up(off + 49152 * 2, 256);

    bool mfma_ok = (off <= ws_size);
    bool csr_ok  = (csr_end <= ws_size);

    if (mfma_ok && csr_ok) {
        // pack all five weight matrices
        k_pack<<<(128 * 128 + 255) / 256, 256, 0, stream>>>(Wi1, 128, 128, Wi1h, Wi1l);
        k_pack<<<(128 * 384 + 255) / 256, 256, 0, stream>>>(Wi2, 128, 384, Wi2h, Wi2l);
        k_pack<<<(128 * 256 + 255) / 256, 256, 0, stream>>>(Wvm, 128, 256, Wvh, Wvl);
        k_pack<<<(256 * 128 + 255) / 256, 256, 0, stream>>>(Wm1, 256, 128, Wm1h, Wm1l);
        k_pack<<<(128 * 384 + 255) / 256, 256, 0, stream>>>(Wm2, 128, 384, Wm2h, Wm2l);

        k1_mfma<<<(n_nodes + 15) / 16, 256, 0, stream>>>(
            s, Wi1h, Wi1l, Wi2h, Wi2l, bi1, bi2, x, n_nodes);

        hipMemsetAsync(head, 0, (size_t)n_nodes * 4, stream);
        k_hist<<<(n_edges + 255) / 256, 256, 0, stream>>>(senders, head, n_edges);
        k_scan<<<1, 1024, 0, stream>>>(head, starts, n_nodes);
        k_scatter<<<(n_edges + 255) / 256, 256, 0, stream>>>(senders, head, eord, n_edges);
        k2_csr<<<n_nodes, 256, 0, stream>>>(
            s, v, x, dir, Wij, recv, starts, eord, out, n_nodes);

        k3_mfma<<<(n_nodes + 15) / 16, 256, 0, stream>>>(
            Wvh, Wvl, Wm1h, Wm1l, Wm2h, Wm2l, bm1, bm2, out, n_nodes);
    } else if (csr_ok) {
        k1_mlp_x<<<(n_nodes + 31) / 32, 128, 0, stream>>>(s, Wi1, bi1, Wi2, bi2, x, n_nodes);
        hipMemsetAsync(head, 0, (size_t)n_nodes * 4, stream);
        k_hist<<<(n_edges + 255) / 256, 256, 0, stream>>>(senders, head, n_edges);
        k_scan<<<1, 1024, 0, stream>>>(head, starts, n_nodes);
        k_scatter<<<(n_edges + 255) / 256, 256, 0, stream>>>(senders, head, eord, n_edges);
        k2_csr<<<n_nodes, 256, 0, stream>>>(
            s, v, x, dir, Wij, recv, starts, eord, out, n_nodes);
        k3_update<<<(n_nodes + NT3 - 1) / NT3, 256, 0, stream>>>(
            Wvm, Wm1, bm1, Wm2, bm2, out, n_nodes, 1.0f);
    } else {
        k1_mlp_x<<<(n_nodes + 31) / 32, 128, 0, stream>>>(s, Wi1, bi1, Wi2, bi2, x, n_nodes);
        k0_init<<<(n_nodes * 128 + 255) / 256, 256, 0, stream>>>(
            (const float4*)s, (const float4*)v, (float4*)out, n_nodes);
        k2_edges<<<(n_edges + 1) / 2, 256, 0, stream>>>(
            x, v, dir, Wij, senders, recv, out, n_edges);
        k3_update<<<(n_nodes + NT3 - 1) / NT3, 256, 0, stream>>>(
            Wvm, Wm1, bm1, Wm2, bm2, out, n_nodes, EPSILON);
    }
}

// Round 4
// 763.446 us; speedup vs baseline: 2.5267x; 1.1170x over previous
//
#include <hip/hip_runtime.h>

#define H 128
#define EPSILON 0.7071067811865476f
#define NEPS 1e-8f
#define NT3 12

typedef short bf16x8 __attribute__((ext_vector_type(8)));
typedef float f32x4 __attribute__((ext_vector_type(4)));

__device__ __forceinline__ float silu_f(float x) {
    return x / (1.0f + __expf(-x));
}

// split f32 into bf16 hi + bf16 lo (RNE)
__device__ __forceinline__ void split_bf(float w, unsigned short& h, unsigned short& l) {
    unsigned ub = __float_as_uint(w);
    unsigned h16 = (ub + 0x7FFF + ((ub >> 16) & 1)) >> 16;
    float hf = __uint_as_float(h16 << 16);
    float r = w - hf;
    unsigned ur = __float_as_uint(r);
    unsigned l16 = (ur + 0x7FFF + ((ur >> 16) & 1)) >> 16;
    h = (unsigned short)h16; l = (unsigned short)l16;
}
__device__ __forceinline__ unsigned short bfround(float w) {
    unsigned ub = __float_as_uint(w);
    return (unsigned short)((ub + 0x7FFF + ((ub >> 16) & 1)) >> 16);
}
__device__ __forceinline__ float bfu(unsigned short u) { return __uint_as_float(((unsigned)u) << 16); }

__device__ __forceinline__ f32x4 mfma3(bf16x8 ah, bf16x8 al, bf16x8 bh, bf16x8 bl, f32x4 acc) {
    acc = __builtin_amdgcn_mfma_f32_16x16x32_bf16(ah, bh, acc, 0, 0, 0);
    acc = __builtin_amdgcn_mfma_f32_16x16x32_bf16(al, bh, acc, 0, 0, 0);
    acc = __builtin_amdgcn_mfma_f32_16x16x32_bf16(ah, bl, acc, 0, 0, 0);
    return acc;
}

// ---------------- pack weights K x N -> fragment-major bf16 hi/lo ----------------
__global__ void k_pack(const float* __restrict__ W, int K, int N,
                       unsigned short* __restrict__ hi, unsigned short* __restrict__ lo) {
    int tid = blockIdx.x * blockDim.x + threadIdx.x;
    int total = K * N;
    if (tid >= total) return;
    int CT = N >> 4;
    int j = tid & 7;
    int l = (tid >> 3) & 63;
    int rest = tid >> 9;
    int ct = rest % CT;
    int ks = rest / CT;
    int row = ks * 32 + ((l >> 4) << 3) + j;
    int col = ct * 16 + (l & 15);
    float w = W[(size_t)row * N + col];
    unsigned short h16, l16;
    split_bf(w, h16, l16);
    hi[tid] = h16; lo[tid] = l16;
}

// ---------------- K1 (MFMA): x = silu(s@Wi1+bi1)@Wi2+bi2, 16 nodes/block ----------------
__global__ __launch_bounds__(256, 4) void k1_mfma(
        const float* __restrict__ s,
        const unsigned short* __restrict__ W1h, const unsigned short* __restrict__ W1l,
        const unsigned short* __restrict__ W2h, const unsigned short* __restrict__ W2l,
        const float* __restrict__ bi1, const float* __restrict__ bi2,
        float* __restrict__ x, int n_nodes) {
    __shared__ unsigned short Ahi[16 * 136], Alo[16 * 136];
    __shared__ unsigned short Hhi[16 * 136], Hlo[16 * 136];
    int t = threadIdx.x;
    int node0 = blockIdx.x * 16;
    int wv = t >> 6, lane = t & 63;
    int g = lane >> 4, cl = lane & 15;

    #pragma unroll
    for (int i = 0; i < 8; ++i) {
        int flat = t + i * 256;
        int n = flat >> 7, k = flat & 127;
        int node = node0 + n; if (node >= n_nodes) node = n_nodes - 1;
        unsigned short h16, l16;
        split_bf(s[(size_t)node * 128 + k], h16, l16);
        Ahi[n * 136 + k] = h16; Alo[n * 136 + k] = l16;
    }
    __syncthreads();

    f32x4 acc1[2] = {};
    #pragma unroll
    for (int ks = 0; ks < 4; ++ks) {
        bf16x8 ah = *(const bf16x8*)&Ahi[cl * 136 + ks * 32 + g * 8];
        bf16x8 al = *(const bf16x8*)&Alo[cl * 136 + ks * 32 + g * 8];
        #pragma unroll
        for (int c = 0; c < 2; ++c) {
            int ct = wv * 2 + c;
            bf16x8 bh = *(const bf16x8*)&W1h[((size_t)(ks * 8 + ct) * 64 + lane) * 8];
            bf16x8 bl = *(const bf16x8*)&W1l[((size_t)(ks * 8 + ct) * 64 + lane) * 8];
            acc1[c] = mfma3(ah, al, bh, bl, acc1[c]);
        }
    }
    #pragma unroll
    for (int c = 0; c < 2; ++c) {
        int col = (wv * 2 + c) * 16 + cl;
        float bias = bi1[col];
        #pragma unroll
        for (int r = 0; r < 4; ++r) {
            float hval = silu_f(acc1[c][r] + bias);
            unsigned short h16, l16; split_bf(hval, h16, l16);
            int row = g * 4 + r;
            Hhi[row * 136 + col] = h16; Hlo[row * 136 + col] = l16;
        }
    }
    __syncthreads();

    f32x4 acc2[6] = {};
    #pragma unroll
    for (int ks = 0; ks < 4; ++ks) {
        bf16x8 ah = *(const bf16x8*)&Hhi[cl * 136 + ks * 32 + g * 8];
        bf16x8 al = *(const bf16x8*)&Hlo[cl * 136 + ks * 32 + g * 8];
        #pragma unroll
        for (int c = 0; c < 6; ++c) {
            int ct = wv * 6 + c;
            bf16x8 bh = *(const bf16x8*)&W2h[((size_t)(ks * 24 + ct) * 64 + lane) * 8];
            bf16x8 bl = *(const bf16x8*)&W2l[((size_t)(ks * 24 + ct) * 64 + lane) * 8];
            acc2[c] = mfma3(ah, al, bh, bl, acc2[c]);
        }
    }
    #pragma unroll
    for (int c = 0; c < 6; ++c) {
        int col = (wv * 6 + c) * 16 + cl;
        float bias = bi2[col];
        #pragma unroll
        for (int r = 0; r < 4; ++r) {
            int node = node0 + g * 4 + r;
            if (node < n_nodes) x[(size_t)node * 384 + col] = acc2[c][r] + bias;
        }
    }
}

// ---------------- CSR build: hist -> wave-aggregated alloc -> scatter ----------------
__global__ void k_hist(const int* __restrict__ senders, int* __restrict__ cnt, int n_edges) {
    int e = blockIdx.x * blockDim.x + threadIdx.x;
    if (e < n_edges) atomicAdd(&cnt[senders[e]], 1);
}

__global__ void k_alloc(const int* __restrict__ cnt, int* __restrict__ starts,
                        int* __restrict__ head, int* __restrict__ cursor, int n) {
    int i = blockIdx.x * blockDim.x + threadIdx.x;
    int lane = threadIdx.x & 63;
    int c = (i < n) ? cnt[i] : 0;
    int pref = c;
    #pragma unroll
    for (int off = 1; off < 64; off <<= 1) {
        int up = __shfl_up(pref, off, 64);
        if (lane >= off) pref += up;
    }
    int total = __shfl(pref, 63, 64);
    int base = 0;
    if (lane == 63) base = atomicAdd(cursor, total);
    base = __shfl(base, 63, 64);
    if (i < n) { int p = base + pref - c; starts[i] = p; head[i] = p; }
}

__global__ void k_scatter(const int* __restrict__ senders, int* __restrict__ head,
                          int* __restrict__ eord, int n_edges) {
    int e = blockIdx.x * blockDim.x + threadIdx.x;
    if (e < n_edges) {
        int p = atomicAdd(&head[senders[e]], 1);
        eord[p] = e;
    }
}

// ---------------- K2 (CSR): per-node gather-accumulate, float4, 8 edge slots ----------------
__global__ __launch_bounds__(256) void k2_csr(
        const float4* __restrict__ s4, const float4* __restrict__ v4,
        const float4* __restrict__ x4, const float* __restrict__ dir,
        const float4* __restrict__ w4, const int* __restrict__ receivers,
        const int* __restrict__ starts, const int* __restrict__ cnt,
        const int* __restrict__ eord, float4* __restrict__ out4, int n_nodes) {
    __shared__ float4 red[8][128];
    int node = blockIdx.x;
    int t = threadIdx.x;
    int slot = t >> 5, lane = t & 31;
    int beg = starts[node], num = cnt[node];
    float4 ds  = {0.f, 0.f, 0.f, 0.f};
    float4 dv0 = {0.f, 0.f, 0.f, 0.f};
    float4 dv1 = {0.f, 0.f, 0.f, 0.f};
    float4 dv2 = {0.f, 0.f, 0.f, 0.f};
    for (int q = slot; q < num; q += 8) {
        int e = eord[beg + q];
        int r = receivers[e];
        const float4* we = w4 + (size_t)e * 96;
        const float4* xr = x4 + (size_t)r * 96;
        const float4* vr = v4 + (size_t)r * 96;
        float4 wa = we[lane], wb = we[32 + lane], wc = we[64 + lane];
        float4 xa = xr[lane], xb = xr[32 + lane], xc = xr[64 + lane];
        float4 va = vr[lane], vb = vr[32 + lane], vc = vr[64 + lane];
        float d0 = dir[3 * (size_t)e + 0];
        float d1 = dir[3 * (size_t)e + 1];
        float d2 = dir[3 * (size_t)e + 2];
        float bx = wb.x * xb.x, by = wb.y * xb.y, bz = wb.z * xb.z, bw = wb.w * xb.w;
        float cx = wc.x * xc.x, cy = wc.y * xc.y, cz = wc.z * xc.z, cw = wc.w * xc.w;
        ds.x += wa.x * xa.x; ds.y += wa.y * xa.y; ds.z += wa.z * xa.z; ds.w += wa.w * xa.w;
        dv0.x += bx * d0 + cx * va.x; dv0.y += by * d0 + cy * va.y;
        dv0.z += bz * d0 + cz * va.z; dv0.w += bw * d0 + cw * va.w;
        dv1.x += bx * d1 + cx * vb.x; dv1.y += by * d1 + cy * vb.y;
        dv1.z += bz * d1 + cz * vb.z; dv1.w += bw * d1 + cw * vb.w;
        dv2.x += bx * d2 + cx * vc.x; dv2.y += by * d2 + cy * vc.y;
        dv2.z += bz * d2 + cz * vc.z; dv2.w += bw * d2 + cw * vc.w;
    }
    red[slot][lane]      = ds;
    red[slot][32 + lane] = dv0;
    red[slot][64 + lane] = dv1;
    red[slot][96 + lane] = dv2;
    __syncthreads();
    if (t < 128) {
        float4 acc = red[0][t];
        #pragma unroll
        for (int q2 = 1; q2 < 8; ++q2) {
            float4 r2 = red[q2][t];
            acc.x += r2.x; acc.y += r2.y; acc.z += r2.z; acc.w += r2.w;
        }
        int which = t >> 5, hh = t & 31;
        float4 base;
        if (which == 0) base = s4[(size_t)node * 32 + hh];
        else            base = v4[(size_t)node * 96 + (size_t)(which - 1) * 32 + hh];
        float4 o;
        o.x = (base.x + acc.x) * EPSILON;
        o.y = (base.y + acc.y) * EPSILON;
        o.z = (base.z + acc.z) * EPSILON;
        o.w = (base.w + acc.w) * EPSILON;
        out4[(size_t)node * 128 + t] = o;
    }
}

// ---------------- K3 (MFMA, pooled LDS 76KB, 2 blocks/CU): fused update ----------------
__global__ __launch_bounds__(256, 2) void k3_mfma(
        const unsigned short* __restrict__ Wvh, const unsigned short* __restrict__ Wvl,
        const unsigned short* __restrict__ W1h, const unsigned short* __restrict__ W1l,
        const unsigned short* __restrict__ W2h, const unsigned short* __restrict__ W2l,
        const float* __restrict__ bm1, const float* __restrict__ bm2,
        float* __restrict__ out, int n_nodes) {
    // LDS pool (76 KB):
    //  [0, 26112)      Ahi/Alo : v_mid bf16 hi/lo, 48x136 each   (alive: phase0 -> final)
    //  [26112, 39168)  vlb     : v_l bf16, 48x136                (alive: gemm1 -> final)
    //  [39168, 52224)  vrc     : v_r bf16, 48x136                (alive: gemm1 -> phase2)
    //  [52224, 69120)  Thi/Tlo : ts bf16 hi/lo, 16x264 each      (alive: phase2 -> gemm2)
    //  [69120, 77824)  Hhi/Hlo : h1 bf16 hi/lo, 16x136 each      (alive: gemm2 -> gemm3)
    //  C3 f32 16x400 overlays [39168, 64768) (vrc+T, both dead by gemm3 epilogue)
    __shared__ __align__(16) char pool[77824];
    unsigned short* Ahi = (unsigned short*)pool;
    unsigned short* Alo = Ahi + 48 * 136;
    unsigned short* vlb = (unsigned short*)(pool + 26112);
    unsigned short* vrc = (unsigned short*)(pool + 39168);
    unsigned short* Thi = (unsigned short*)(pool + 52224);
    unsigned short* Tlo = Thi + 16 * 264;
    unsigned short* Hhi = (unsigned short*)(pool + 69120);
    unsigned short* Hlo = Hhi + 16 * 136;
    float* C3 = (float*)(pool + 39168);     // [16][400]

    int t = threadIdx.x;
    int node0 = blockIdx.x * 16;
    int wv = t >> 6, lane = t & 63;
    int g = lane >> 4, cl = lane & 15;

    float smid_reg[8], dot_reg[8];

    // ---- phase 0: stage v_mid (48x128) bf16 hi/lo; s_mid -> registers ----
    #pragma unroll
    for (int i = 0; i < 24; ++i) {
        int flat = t + i * 256;
        int row = flat >> 7, k = flat & 127;
        int n = row / 3, d = row - n * 3;
        int node = node0 + n; if (node >= n_nodes) node = n_nodes - 1;
        float val = out[(size_t)node * 512 + 128 + d * 128 + k];
        unsigned short h16, l16; split_bf(val, h16, l16);
        Ahi[row * 136 + k] = h16; Alo[row * 136 + k] = l16;
    }
    #pragma unroll
    for (int i = 0; i < 8; ++i) {
        int flat = t + i * 256;
        int n = flat >> 7, k = flat & 127;
        int node = node0 + n; if (node >= n_nodes) node = n_nodes - 1;
        smid_reg[i] = out[(size_t)node * 512 + k];
    }
    __syncthreads();

    // ---- GEMM1: (48x128)@(128x256) -> v_l | v_r (bf16 storage) ----
    #pragma unroll
    for (int rt = 0; rt < 3; ++rt) {
        bf16x8 ah[4], al[4];
        #pragma unroll
        for (int ks = 0; ks < 4; ++ks) {
            ah[ks] = *(const bf16x8*)&Ahi[(rt * 16 + cl) * 136 + ks * 32 + g * 8];
            al[ks] = *(const bf16x8*)&Alo[(rt * 16 + cl) * 136 + ks * 32 + g * 8];
        }
        f32x4 acc[4] = {};
        #pragma unroll
        for (int ks = 0; ks < 4; ++ks) {
            #pragma unroll
            for (int c = 0; c < 4; ++c) {
                int ct = wv * 4 + c;
                bf16x8 bh = *(const bf16x8*)&Wvh[((size_t)(ks * 16 + ct) * 64 + lane) * 8];
                bf16x8 bl = *(const bf16x8*)&Wvl[((size_t)(ks * 16 + ct) * 64 + lane) * 8];
                acc[c] = mfma3(ah[ks], al[ks], bh, bl, acc[c]);
            }
        }
        #pragma unroll
        for (int c = 0; c < 4; ++c) {
            int col = (wv * 4 + c) * 16 + cl;
            unsigned short* dst = (col < 128) ? vlb : vrc;
            int cc = col & 127;
            #pragma unroll
            for (int r = 0; r < 4; ++r)
                dst[(rt * 16 + g * 4 + r) * 136 + cc] = bfround(acc[c][r]);
        }
    }
    __syncthreads();

    // ---- phase 2: v_norm, dot -> registers; build ts ----
    #pragma unroll
    for (int i = 0; i < 8; ++i) {
        int flat = t + i * 256;
        int n = flat >> 7, h = flat & 127;
        float r0 = bfu(vrc[(3 * n + 0) * 136 + h]);
        float r1 = bfu(vrc[(3 * n + 1) * 136 + h]);
        float r2 = bfu(vrc[(3 * n + 2) * 136 + h]);
        float l0 = bfu(vlb[(3 * n + 0) * 136 + h]);
        float l1 = bfu(vlb[(3 * n + 1) * 136 + h]);
        float l2 = bfu(vlb[(3 * n + 2) * 136 + h]);
        float nrm = sqrtf(r0 * r0 + r1 * r1 + r2 * r2 + NEPS);
        dot_reg[i] = r0 * l0 + r1 * l1 + r2 * l2;
        unsigned short h16, l16;
        split_bf(nrm, h16, l16);
        Thi[n * 264 + 128 + h] = h16; Tlo[n * 264 + 128 + h] = l16;
        split_bf(smid_reg[i], h16, l16);
        Thi[n * 264 + h] = h16; Tlo[n * 264 + h] = l16;
    }
    __syncthreads();

    // ---- GEMM2: (16x256)@(256x128) + bm1 -> silu -> h1 ----
    f32x4 acc2[2] = {};
    #pragma unroll
    for (int ks = 0; ks < 8; ++ks) {
        bf16x8 ah = *(const bf16x8*)&Thi[cl * 264 + ks * 32 + g * 8];
        bf16x8 al = *(const bf16x8*)&Tlo[cl * 264 + ks * 32 + g * 8];
        #pragma unroll
        for (int c = 0; c < 2; ++c) {
            int ct = wv * 2 + c;
            bf16x8 bh = *(const bf16x8*)&W1h[((size_t)(ks * 8 + ct) * 64 + lane) * 8];
            bf16x8 bl = *(const bf16x8*)&W1l[((size_t)(ks * 8 + ct) * 64 + lane) * 8];
            acc2[c] = mfma3(ah, al, bh, bl, acc2[c]);
        }
    }
    #pragma unroll
    for (int c = 0; c < 2; ++c) {
        int col = (wv * 2 + c) * 16 + cl;
        float bias = bm1[col];
        #pragma unroll
        for (int r = 0; r < 4; ++r) {
            float hval = silu_f(acc2[c][r] + bias);
            unsigned short h16, l16; split_bf(hval, h16, l16);
            int row = g * 4 + r;
            Hhi[row * 136 + col] = h16; Hlo[row * 136 + col] = l16;
        }
    }
    __syncthreads();

    // ---- GEMM3: (16x128)@(128x384) + bm2 -> C3 (overlays vrc+ts) ----
    f32x4 acc3[6] = {};
    #pragma unroll
    for (int ks = 0; ks < 4; ++ks) {
        bf16x8 ah = *(const bf16x8*)&Hhi[cl * 136 + ks * 32 + g * 8];
        bf16x8 al = *(const bf16x8*)&Hlo[cl * 136 + ks * 32 + g * 8];
        #pragma unroll
        for (int c = 0; c < 6; ++c) {
            int ct = wv * 6 + c;
            bf16x8 bh = *(const bf16x8*)&W2h[((size_t)(ks * 24 + ct) * 64 + lane) * 8];
            bf16x8 bl = *(const bf16x8*)&W2l[((size_t)(ks * 24 + ct) * 64 + lane) * 8];
            acc3[c] = mfma3(ah, al, bh, bl, acc3[c]);
        }
    }
    __syncthreads();   // all reads of vrc/T done before C3 overwrite
    #pragma unroll
    for (int c = 0; c < 6; ++c) {
        int col = (wv * 6 + c) * 16 + cl;
        float bias = bm2[col];
        #pragma unroll
        for (int r = 0; r < 4; ++r)
            C3[(g * 4 + r) * 400 + col] = acc3[c][r] + bias;
    }
    __syncthreads();

    // ---- final combine ----
    #pragma unroll
    for (int i = 0; i < 8; ++i) {
        int flat = t + i * 256;
        int n = flat >> 7, h = flat & 127;
        int node = node0 + n;
        if (node >= n_nodes) continue;
        float ds_u = C3[n * 400 + h];
        float dv_u = C3[n * 400 + 128 + h];
        float dsv  = C3[n * 400 + 256 + h] * dot_reg[i];
        out[(size_t)node * 512 + h] = (smid_reg[i] + ds_u + dsv) * EPSILON;
        #pragma unroll
        for (int d = 0; d < 3; ++d) {
            int row = 3 * n + d;
            float vmid = bfu(Ahi[row * 136 + h]) + bfu(Alo[row * 136 + h]);
            float vl_v = bfu(vlb[row * 136 + h]);
            out[(size_t)node * 512 + 128 + d * 128 + h] = (vmid + vl_v * dv_u) * EPSILON;
        }
    }
}

// ---------------- fallback: vector k1/k3 (kept for ws-too-small safety) ----------------
__global__ __launch_bounds__(128) void k1_mlp_x(
        const float* __restrict__ s,
        const float* __restrict__ Wi1, const float* __restrict__ bi1,
        const float* __restrict__ Wi2, const float* __restrict__ bi2,
        float* __restrict__ x, int n_nodes) {
    __shared__ float s_lds[32][H];
    __shared__ float h_lds[32][H];
    int j = threadIdx.x;
    int node0 = blockIdx.x * 32;
    #pragma unroll
    for (int n = 0; n < 32; ++n) {
        int node = node0 + n; if (node >= n_nodes) node = n_nodes - 1;
        s_lds[n][j] = s[(size_t)node * H + j];
    }
    __syncthreads();
    float acc[32];
    #pragma unroll
    for (int n = 0; n < 32; ++n) acc[n] = bi1[j];
    for (int k = 0; k < H; k += 4) {
        float w0 = Wi1[(k + 0) * H + j];
        float w1 = Wi1[(k + 1) * H + j];
        float w2 = Wi1[(k + 2) * H + j];
        float w3 = Wi1[(k + 3) * H + j];
        #pragma unroll
        for (int n = 0; n < 32; ++n) {
            float4 sv = *reinterpret_cast<const float4*>(&s_lds[n][k]);
            acc[n] += sv.x * w0 + sv.y * w1 + sv.z * w2 + sv.w * w3;
        }
    }
    #pragma unroll
    for (int n = 0; n < 32; ++n) h_lds[n][j] = silu_f(acc[n]);
    __syncthreads();
    for (int c = 0; c < 3; ++c) {
        int col = c * H + j;
        float a2[32];
        #pragma unroll
        for (int n = 0; n < 32; ++n) a2[n] = bi2[col];
        for (int k = 0; k < H; k += 4) {
            float w0 = Wi2[(k + 0) * 384 + col];
            float w1 = Wi2[(k + 1) * 384 + col];
            float w2 = Wi2[(k + 2) * 384 + col];
            float w3 = Wi2[(k + 3) * 384 + col];
            #pragma unroll
            for (int n = 0; n < 32; ++n) {
                float4 hv = *reinterpret_cast<const float4*>(&h_lds[n][k]);
                a2[n] += hv.x * w0 + hv.y * w1 + hv.z * w2 + hv.w * w3;
            }
        }
        #pragma unroll
        for (int n = 0; n < 32; ++n) {
            int node = node0 + n;
            if (node < n_nodes) x[(size_t)node * 384 + col] = a2[n];
        }
    }
}

__global__ __launch_bounds__(256) void k3_update(
        const float* __restrict__ Wvm,
        const float* __restrict__ Wm1, const float* __restrict__ bm1,
        const float* __restrict__ Wm2, const float* __restrict__ bm2,
        float* __restrict__ out, int n_nodes) {
    __shared__ float v_lds[NT3][3][H];
    __shared__ float vl_lds[NT3][3][H];
    __shared__ float ts_lds[NT3][2 * H];
    __shared__ float dot_lds[NT3][H];
    int t = threadIdx.x;
    int node0 = blockIdx.x * NT3;
    for (int idx = t; idx < NT3 * 512; idx += 256) {
        int n = idx >> 9, r = idx & 511;
        int node = node0 + n; if (node >= n_nodes) node = n_nodes - 1;
        float val = out[(size_t)node * 512 + r];
        if (r < 128) ts_lds[n][r] = val;
        else         v_lds[n][(r >> 7) - 1][r & 127] = val;
    }
    __syncthreads();
    float acc[NT3 * 3];
    #pragma unroll
    for (int i = 0; i < NT3 * 3; ++i) acc[i] = 0.f;
    int j = t;
    for (int k = 0; k < H; k += 4) {
        float w0 = Wvm[(k + 0) * 256 + j];
        float w1 = Wvm[(k + 1) * 256 + j];
        float w2 = Wvm[(k + 2) * 256 + j];
        float w3 = Wvm[(k + 3) * 256 + j];
        #pragma unroll
        for (int n = 0; n < NT3; ++n) {
            #pragma unroll
            for (int d = 0; d < 3; ++d) {
                float4 vv = *reinterpret_cast<const float4*>(&v_lds[n][d][k]);
                acc[n * 3 + d] += vv.x * w0 + vv.y * w1 + vv.z * w2 + vv.w * w3;
            }
        }
    }
    if (j < 128) {
        #pragma unroll
        for (int n = 0; n < NT3; ++n)
            #pragma unroll
            for (int d = 0; d < 3; ++d)
                vl_lds[n][d][j] = acc[n * 3 + d];
    }
    __syncthreads();
    if (j >= 128) {
        int h = j - 128;
        #pragma unroll
        for (int n = 0; n < NT3; ++n) {
            float a0 = acc[n * 3 + 0], a1 = acc[n * 3 + 1], a2 = acc[n * 3 + 2];
            ts_lds[n][128 + h] = sqrtf(a0 * a0 + a1 * a1 + a2 * a2 + NEPS);
            dot_lds[n][h] = a0 * vl_lds[n][0][h] + a1 * vl_lds[n][1][h] + a2 * vl_lds[n][2][h];
        }
    }
    __syncthreads();
    int jj = t & 127, g = t >> 7;
    float hacc[6];
    #pragma unroll
    for (int n2 = 0; n2 < 6; ++n2) hacc[n2] = bm1[jj];
    for (int k = 0; k < 256; k += 4) {
        float w0 = Wm1[(k + 0) * H + jj];
        float w1 = Wm1[(k + 1) * H + jj];
        float w2 = Wm1[(k + 2) * H + jj];
        float w3 = Wm1[(k + 3) * H + jj];
        #pragma unroll
        for (int n2 = 0; n2 < 6; ++n2) {
            float4 tv = *reinterpret_cast<const float4*>(&ts_lds[g * 6 + n2][k]);
            hacc[n2] += tv.x * w0 + tv.y * w1 + tv.z * w2 + tv.w * w3;
        }
    }
    __syncthreads();
    #pragma unroll
    for (int n2 = 0; n2 < 6; ++n2) ts_lds[g * 6 + n2][128 + jj] = silu_f(hacc[n2]);
    __syncthreads();
    float o0[6], o1[6], o2[6];
    #pragma unroll
    for (int n2 = 0; n2 < 6; ++n2) {
        o0[n2] = bm2[jj]; o1[n2] = bm2[128 + jj]; o2[n2] = bm2[256 + jj];
    }
    for (int k = 0; k < H; k += 4) {
        #pragma unroll
        for (int kk = 0; kk < 4; ++kk) {
            float wa = Wm2[(k + kk) * 384 + jj];
            float wb = Wm2[(k + kk) * 384 + 128 + jj];
            float wc = Wm2[(k + kk) * 384 + 256 + jj];
            #pragma unroll
            for (int n2 = 0; n2 < 6; ++n2) {
                float hv = ts_lds[g * 6 + n2][128 + k + kk];
                o0[n2] += hv * wa; o1[n2] += hv * wb; o2[n2] += hv * wc;
            }
        }
    }
    #pragma unroll
    for (int n2 = 0; n2 < 6; ++n2) {
        int n = g * 6 + n2;
        int node = node0 + n;
        if (node < n_nodes) {
            float s_mid = ts_lds[n][jj];
            float ds_u = o0[n2];
            float dvs  = o1[n2];
            float dsv  = o2[n2] * dot_lds[n][jj];
            out[(size_t)node * 512 + jj] = (s_mid + ds_u + dsv) * EPSILON;
            #pragma unroll
            for (int d = 0; d < 3; ++d)
                out[(size_t)node * 512 + 128 + d * 128 + jj] =
                    (v_lds[n][d][jj] + vl_lds[n][d][jj] * dvs) * EPSILON;
        }
    }
}

static inline size_t align_up(size_t x, size_t a) { return (x + a - 1) / a * a; }

extern "C" void kernel_launch(void* const* d_in, const int* in_sizes, int n_in,
                              void* d_out, int out_size, void* d_ws, size_t ws_size,
                              hipStream_t stream) {
    const float* s       = (const float*)d_in[0];
    const float* v       = (const float*)d_in[1];
    const float* dir     = (const float*)d_in[2];
    const float* Wij     = (const float*)d_in[3];
    const int*   senders = (const int*)d_in[4];
    const int*   recv    = (const int*)d_in[5];
    const float* Wi1     = (const float*)d_in[6];
    const float* bi1     = (const float*)d_in[7];
    const float* Wi2     = (const float*)d_in[8];
    const float* bi2     = (const float*)d_in[9];
    const float* Wm1     = (const float*)d_in[10];
    const float* bm1     = (const float*)d_in[11];
    const float* Wm2     = (const float*)d_in[12];
    const float* bm2     = (const float*)d_in[13];
    const float* Wvm     = (const float*)d_in[14];

    int n_nodes = in_sizes[0] / H;
    int n_edges = in_sizes[4];
    float* out = (float*)d_out;

    // workspace layout
    char* ws = (char*)d_ws;
    size_t off = 0;
    float* x      = (float*)(ws + off); off = align_up(off + (size_t)n_nodes * 384 * 4, 256);
    int*   starts = (int*)(ws + off);   off = align_up(off + (size_t)n_nodes * 4, 256);
    int*   cnt    = (int*)(ws + off);   off = align_up(off + (size_t)(n_nodes + 1) * 4, 256);
    int*   cursor = cnt + n_nodes;      // zeroed together with cnt
    int*   head   = (int*)(ws + off);   off = align_up(off + (size_t)n_nodes * 4, 256);
    int*   eord   = (int*)(ws + off);   off = align_up(off + (size_t)n_edges * 4, 256);
    size_t csr_end = off;
    unsigned short* Wi1h = (unsigned short*)(ws + off); off = align_up(off + 16384 * 2, 256);
    unsigned short* Wi1l = (unsigned short*)(ws + off); off = align_up(off + 16384 * 2, 256);
    unsigned short* Wi2h = (unsigned short*)(ws + off); off = align_up(off + 49152 * 2, 256);
    unsigned short* Wi2l = (unsigned short*)(ws + off); off = align_up(off + 49152 * 2, 256);
    unsigned short* Wvh  = (unsigned short*)(ws + off); off = align_up(off + 32768 * 2, 256);
    unsigned short* Wvl  = (unsigned short*)(ws + off); off = align_up(off + 32768 * 2, 256);
    unsigned short* Wm1h = (unsigned short*)(ws + off); off = align_up(off + 32768 * 2, 256);
    unsigned short* Wm1l = (unsigned short*)(ws + off); off = align_up(off + 32768 * 2, 256);
    unsigned short* Wm2h = (unsigned short*)(ws + off); off = align_up(off + 49152 * 2, 256);
    unsigned short* Wm2l = (unsigned short*)(ws + off); off = align_up(off + 49152 * 2, 256);

    bool mfma_ok = (off <= ws_size);
    bool csr_ok  = (csr_end <= ws_size);
    if (!csr_ok) return;   // ws is known-large (>3 GB); CSR always fits

    // CSR build
    hipMemsetAsync(cnt, 0, (size_t)(n_nodes + 1) * 4, stream);
    k_hist<<<(n_edges + 255) / 256, 256, 0, stream>>>(senders, cnt, n_edges);
    k_alloc<<<(n_nodes + 255) / 256, 256, 0, stream>>>(cnt, starts, head, cursor, n_nodes);
    k_scatter<<<(n_edges + 255) / 256, 256, 0, stream>>>(senders, head, eord, n_edges);

    if (mfma_ok) {
        k_pack<<<(128 * 128 + 255) / 256, 256, 0, stream>>>(Wi1, 128, 128, Wi1h, Wi1l);
        k_pack<<<(128 * 384 + 255) / 256, 256, 0, stream>>>(Wi2, 128, 384, Wi2h, Wi2l);
        k_pack<<<(128 * 256 + 255) / 256, 256, 0, stream>>>(Wvm, 128, 256, Wvh, Wvl);
        k_pack<<<(256 * 128 + 255) / 256, 256, 0, stream>>>(Wm1, 256, 128, Wm1h, Wm1l);
        k_pack<<<(128 * 384 + 255) / 256, 256, 0, stream>>>(Wm2, 128, 384, Wm2h, Wm2l);

        k1_mfma<<<(n_nodes + 15) / 16, 256, 0, stream>>>(
            s, Wi1h, Wi1l, Wi2h, Wi2l, bi1, bi2, x, n_nodes);

        k2_csr<<<n_nodes, 256, 0, stream>>>(
            (const float4*)s, (const float4*)v, (const float4*)x, dir,
            (const float4*)Wij, recv, starts, cnt, eord, (float4*)out, n_nodes);

        k3_mfma<<<(n_nodes + 15) / 16, 256, 0, stream>>>(
            Wvh, Wvl, Wm1h, Wm1l, Wm2h, Wm2l, bm1, bm2, out, n_nodes);
    } else {
        k1_mlp_x<<<(n_nodes + 31) / 32, 128, 0, stream>>>(s, Wi1, bi1, Wi2, bi2, x, n_nodes);
        k2_csr<<<n_nodes, 256, 0, stream>>>(
            (const float4*)s, (const float4*)v, (const float4*)x, dir,
            (const float4*)Wij, recv, starts, cnt, eord, (float4*)out, n_nodes);
        k3_update<<<(n_nodes + NT3 - 1) / NT3, 256, 0, stream>>>(
            Wvm, Wm1, bm1, Wm2, bm2, out, n_nodes);
    }
}

// Round 5
// 527.382 us; speedup vs baseline: 3.6578x; 1.4476x over previous
//
#include <hip/hip_runtime.h>

#define H 128
#define EPSILON 0.7071067811865476f
#define NEPS 1e-8f

typedef short bf16x8 __attribute__((ext_vector_type(8)));
typedef float f32x4 __attribute__((ext_vector_type(4)));
typedef unsigned short ushort_t;

__device__ __forceinline__ float silu_f(float x) {
    return x / (1.0f + __expf(-x));
}
__device__ __forceinline__ unsigned short bfround(float w) {
    unsigned ub = __float_as_uint(w);
    return (unsigned short)((ub + 0x7FFF + ((ub >> 16) & 1)) >> 16);
}
__device__ __forceinline__ float bfu(unsigned short u) { return __uint_as_float(((unsigned)u) << 16); }

// ---------------- pack weights K x N -> fragment-major bf16 ----------------
// elem (ks, ct, lane, j) at ((ks*CT+ct)*64+lane)*8+j = W[ks*32+(lane>>4)*8+j][ct*16+(lane&15)]
__global__ void k_pack(const float* __restrict__ W, int K, int N,
                       ushort_t* __restrict__ p) {
    int tid = blockIdx.x * blockDim.x + threadIdx.x;
    int total = K * N;
    if (tid >= total) return;
    int CT = N >> 4;
    int j = tid & 7;
    int l = (tid >> 3) & 63;
    int rest = tid >> 9;
    int ct = rest % CT;
    int ks = rest / CT;
    int row = ks * 32 + ((l >> 4) << 3) + j;
    int col = ct * 16 + (l & 15);
    p[tid] = bfround(W[(size_t)row * N + col]);
}

// ---------------- convert v -> bf16 ----------------
__global__ void k_cvt_v(const float4* __restrict__ v4, ushort4* __restrict__ vb, int n4) {
    int i = blockIdx.x * blockDim.x + threadIdx.x;
    if (i >= n4) return;
    float4 f = v4[i];
    ushort4 u;
    u.x = bfround(f.x); u.y = bfround(f.y); u.z = bfround(f.z); u.w = bfround(f.w);
    vb[i] = u;
}

// ---------------- K1 (MFMA): x = silu(s@Wi1+bi1)@Wi2+bi2 -> bf16 x, 16 nodes/block ----------------
__global__ __launch_bounds__(256, 4) void k1_mfma(
        const float* __restrict__ s,
        const ushort_t* __restrict__ W1p, const ushort_t* __restrict__ W2p,
        const float* __restrict__ bi1, const float* __restrict__ bi2,
        ushort_t* __restrict__ x, int n_nodes) {
    __shared__ ushort_t Ab[16 * 136];
    __shared__ ushort_t Hb[16 * 136];
    int t = threadIdx.x;
    int node0 = blockIdx.x * 16;
    int wv = t >> 6, lane = t & 63;
    int g = lane >> 4, cl = lane & 15;

    #pragma unroll
    for (int i = 0; i < 8; ++i) {
        int flat = t + i * 256;
        int n = flat >> 7, k = flat & 127;
        int node = node0 + n; if (node >= n_nodes) node = n_nodes - 1;
        Ab[n * 136 + k] = bfround(s[(size_t)node * 128 + k]);
    }
    __syncthreads();

    f32x4 acc1[2] = {};
    #pragma unroll
    for (int ks = 0; ks < 4; ++ks) {
        bf16x8 ah = *(const bf16x8*)&Ab[cl * 136 + ks * 32 + g * 8];
        #pragma unroll
        for (int c = 0; c < 2; ++c) {
            int ct = wv * 2 + c;
            bf16x8 bh = *(const bf16x8*)&W1p[((size_t)(ks * 8 + ct) * 64 + lane) * 8];
            acc1[c] = __builtin_amdgcn_mfma_f32_16x16x32_bf16(ah, bh, acc1[c], 0, 0, 0);
        }
    }
    #pragma unroll
    for (int c = 0; c < 2; ++c) {
        int col = (wv * 2 + c) * 16 + cl;
        float bias = bi1[col];
        #pragma unroll
        for (int r = 0; r < 4; ++r) {
            int row = g * 4 + r;
            Hb[row * 136 + col] = bfround(silu_f(acc1[c][r] + bias));
        }
    }
    __syncthreads();

    f32x4 acc2[6] = {};
    #pragma unroll
    for (int ks = 0; ks < 4; ++ks) {
        bf16x8 ah = *(const bf16x8*)&Hb[cl * 136 + ks * 32 + g * 8];
        #pragma unroll
        for (int c = 0; c < 6; ++c) {
            int ct = wv * 6 + c;
            bf16x8 bh = *(const bf16x8*)&W2p[((size_t)(ks * 24 + ct) * 64 + lane) * 8];
            acc2[c] = __builtin_amdgcn_mfma_f32_16x16x32_bf16(ah, bh, acc2[c], 0, 0, 0);
        }
    }
    #pragma unroll
    for (int c = 0; c < 6; ++c) {
        int col = (wv * 6 + c) * 16 + cl;
        float bias = bi2[col];
        #pragma unroll
        for (int r = 0; r < 4; ++r) {
            int node = node0 + g * 4 + r;
            if (node < n_nodes) x[(size_t)node * 384 + col] = bfround(acc2[c][r] + bias);
        }
    }
}

// ---------------- CSR build ----------------
__global__ void k_hist(const int* __restrict__ senders, int* __restrict__ cnt, int n_edges) {
    int e = blockIdx.x * blockDim.x + threadIdx.x;
    if (e < n_edges) atomicAdd(&cnt[senders[e]], 1);
}

__global__ void k_alloc(const int* __restrict__ cnt, int* __restrict__ starts,
                        int* __restrict__ head, int* __restrict__ cursor, int n) {
    int i = blockIdx.x * blockDim.x + threadIdx.x;
    int lane = threadIdx.x & 63;
    int c = (i < n) ? cnt[i] : 0;
    int pref = c;
    #pragma unroll
    for (int off = 1; off < 64; off <<= 1) {
        int up = __shfl_up(pref, off, 64);
        if (lane >= off) pref += up;
    }
    int total = __shfl(pref, 63, 64);
    int base = 0;
    if (lane == 63) base = atomicAdd(cursor, total);
    base = __shfl(base, 63, 64);
    if (i < n) { int p = base + pref - c; starts[i] = p; head[i] = p; }
}

__global__ void k_scatter(const int* __restrict__ senders, const int* __restrict__ receivers,
                          int* __restrict__ head, int* __restrict__ eord,
                          int* __restrict__ erecv, int n_edges) {
    int e = blockIdx.x * blockDim.x + threadIdx.x;
    if (e < n_edges) {
        int p = atomicAdd(&head[senders[e]], 1);
        eord[p] = e;
        erecv[p] = receivers[e];
    }
}

// ---------------- K2 (CSR): per-node gather-accumulate; Wij fp32, x/v bf16 ----------------
__global__ __launch_bounds__(256) void k2_csr(
        const float4* __restrict__ s4, const ushort_t* __restrict__ vbf,
        const ushort_t* __restrict__ xbf, const float* __restrict__ dir,
        const float4* __restrict__ w4, const int* __restrict__ starts,
        const int* __restrict__ cnt, const int* __restrict__ eord,
        const int* __restrict__ erecv, float4* __restrict__ out4, int n_nodes) {
    __shared__ float4 red[8][128];
    int node = blockIdx.x;
    int t = threadIdx.x;
    int slot = t >> 5, lane = t & 31;
    int beg = starts[node], num = cnt[node];
    float4 ds  = {0.f, 0.f, 0.f, 0.f};
    float4 dv0 = {0.f, 0.f, 0.f, 0.f};
    float4 dv1 = {0.f, 0.f, 0.f, 0.f};
    float4 dv2 = {0.f, 0.f, 0.f, 0.f};
    for (int q = slot; q < num; q += 8) {
        int e = eord[beg + q];
        int r = erecv[beg + q];
        const float4*   we = w4  + (size_t)e * 96;
        const ushort_t* xr = xbf + (size_t)r * 384;
        const ushort_t* vr = vbf + (size_t)r * 384;
        float4 wa = we[lane], wb = we[32 + lane], wc = we[64 + lane];
        ushort4 xa = *(const ushort4*)&xr[4 * lane];
        ushort4 xb = *(const ushort4*)&xr[128 + 4 * lane];
        ushort4 xc = *(const ushort4*)&xr[256 + 4 * lane];
        ushort4 va = *(const ushort4*)&vr[4 * lane];
        ushort4 vb = *(const ushort4*)&vr[128 + 4 * lane];
        ushort4 vc = *(const ushort4*)&vr[256 + 4 * lane];
        float d0 = dir[3 * (size_t)e + 0];
        float d1 = dir[3 * (size_t)e + 1];
        float d2 = dir[3 * (size_t)e + 2];
        float bx = wb.x * bfu(xb.x), by = wb.y * bfu(xb.y), bz = wb.z * bfu(xb.z), bw = wb.w * bfu(xb.w);
        float cx = wc.x * bfu(xc.x), cy = wc.y * bfu(xc.y), cz = wc.z * bfu(xc.z), cw = wc.w * bfu(xc.w);
        ds.x += wa.x * bfu(xa.x); ds.y += wa.y * bfu(xa.y);
        ds.z += wa.z * bfu(xa.z); ds.w += wa.w * bfu(xa.w);
        dv0.x += bx * d0 + cx * bfu(va.x); dv0.y += by * d0 + cy * bfu(va.y);
        dv0.z += bz * d0 + cz * bfu(va.z); dv0.w += bw * d0 + cw * bfu(va.w);
        dv1.x += bx * d1 + cx * bfu(vb.x); dv1.y += by * d1 + cy * bfu(vb.y);
        dv1.z += bz * d1 + cz * bfu(vb.z); dv1.w += bw * d1 + cw * bfu(vb.w);
        dv2.x += bx * d2 + cx * bfu(vc.x); dv2.y += by * d2 + cy * bfu(vc.y);
        dv2.z += bz * d2 + cz * bfu(vc.z); dv2.w += bw * d2 + cw * bfu(vc.w);
    }
    red[slot][lane]      = ds;
    red[slot][32 + lane] = dv0;
    red[slot][64 + lane] = dv1;
    red[slot][96 + lane] = dv2;
    __syncthreads();
    if (t < 128) {
        float4 acc = red[0][t];
        #pragma unroll
        for (int q2 = 1; q2 < 8; ++q2) {
            float4 r2 = red[q2][t];
            acc.x += r2.x; acc.y += r2.y; acc.z += r2.z; acc.w += r2.w;
        }
        int which = t >> 5, hh = t & 31;
        float4 base;
        if (which == 0) base = s4[(size_t)node * 32 + hh];
        else {
            // reconstruct v from bf16? no — read original fp32 v for the residual
            base = ((const float4*)0)[0];  // placeholder, replaced below
        }
        // residual add must use fp32 v: recompute via vbf would lose precision;
        // instead read the fp32 v row directly.
        if (which != 0) {
            const float4* vrow = (const float4*)((const char*)s4 + 0);  // unused
        }
        float4 o;
        o.x = (base.x + acc.x) * EPSILON;
        o.y = (base.y + acc.y) * EPSILON;
        o.z = (base.z + acc.z) * EPSILON;
        o.w = (base.w + acc.w) * EPSILON;
        out4[(size_t)node * 128 + t] = o;
    }
}

// NOTE: k2_csr above is replaced by k2_csr2 (with fp32 v residual); kept minimal.
__global__ __launch_bounds__(256) void k2_csr2(
        const float4* __restrict__ s4, const float4* __restrict__ v4,
        const ushort_t* __restrict__ vbf, const ushort_t* __restrict__ xbf,
        const float* __restrict__ dir, const float4* __restrict__ w4,
        const int* __restrict__ starts, const int* __restrict__ cnt,
        const int* __restrict__ eord, const int* __restrict__ erecv,
        float4* __restrict__ out4, int n_nodes) {
    __shared__ float4 red[8][128];
    int node = blockIdx.x;
    int t = threadIdx.x;
    int slot = t >> 5, lane = t & 31;
    int beg = starts[node], num = cnt[node];
    float4 ds  = {0.f, 0.f, 0.f, 0.f};
    float4 dv0 = {0.f, 0.f, 0.f, 0.f};
    float4 dv1 = {0.f, 0.f, 0.f, 0.f};
    float4 dv2 = {0.f, 0.f, 0.f, 0.f};
    for (int q = slot; q < num; q += 8) {
        int e = eord[beg + q];
        int r = erecv[beg + q];
        const float4*   we = w4  + (size_t)e * 96;
        const ushort_t* xr = xbf + (size_t)r * 384;
        const ushort_t* vr = vbf + (size_t)r * 384;
        float4 wa = we[lane], wb = we[32 + lane], wc = we[64 + lane];
        ushort4 xa = *(const ushort4*)&xr[4 * lane];
        ushort4 xb = *(const ushort4*)&xr[128 + 4 * lane];
        ushort4 xc = *(const ushort4*)&xr[256 + 4 * lane];
        ushort4 va = *(const ushort4*)&vr[4 * lane];
        ushort4 vb = *(const ushort4*)&vr[128 + 4 * lane];
        ushort4 vc = *(const ushort4*)&vr[256 + 4 * lane];
        float d0 = dir[3 * (size_t)e + 0];
        float d1 = dir[3 * (size_t)e + 1];
        float d2 = dir[3 * (size_t)e + 2];
        float bx = wb.x * bfu(xb.x), by = wb.y * bfu(xb.y), bz = wb.z * bfu(xb.z), bw = wb.w * bfu(xb.w);
        float cx = wc.x * bfu(xc.x), cy = wc.y * bfu(xc.y), cz = wc.z * bfu(xc.z), cw = wc.w * bfu(xc.w);
        ds.x += wa.x * bfu(xa.x); ds.y += wa.y * bfu(xa.y);
        ds.z += wa.z * bfu(xa.z); ds.w += wa.w * bfu(xa.w);
        dv0.x += bx * d0 + cx * bfu(va.x); dv0.y += by * d0 + cy * bfu(va.y);
        dv0.z += bz * d0 + cz * bfu(va.z); dv0.w += bw * d0 + cw * bfu(va.w);
        dv1.x += bx * d1 + cx * bfu(vb.x); dv1.y += by * d1 + cy * bfu(vb.y);
        dv1.z += bz * d1 + cz * bfu(vb.z); dv1.w += bw * d1 + cw * bfu(vb.w);
        dv2.x += bx * d2 + cx * bfu(vc.x); dv2.y += by * d2 + cy * bfu(vc.y);
        dv2.z += bz * d2 + cz * bfu(vc.z); dv2.w += bw * d2 + cw * bfu(vc.w);
    }
    red[slot][lane]      = ds;
    red[slot][32 + lane] = dv0;
    red[slot][64 + lane] = dv1;
    red[slot][96 + lane] = dv2;
    __syncthreads();
    if (t < 128) {
        float4 acc = red[0][t];
        #pragma unroll
        for (int q2 = 1; q2 < 8; ++q2) {
            float4 r2 = red[q2][t];
            acc.x += r2.x; acc.y += r2.y; acc.z += r2.z; acc.w += r2.w;
        }
        int which = t >> 5, hh = t & 31;
        float4 base;
        if (which == 0) base = s4[(size_t)node * 32 + hh];
        else            base = v4[(size_t)node * 96 + (size_t)(which - 1) * 32 + hh];
        float4 o;
        o.x = (base.x + acc.x) * EPSILON;
        o.y = (base.y + acc.y) * EPSILON;
        o.z = (base.z + acc.z) * EPSILON;
        o.w = (base.w + acc.w) * EPSILON;
        out4[(size_t)node * 128 + t] = o;
    }
}

// ---------------- K3 (MFMA, single-bf16, pooled LDS ~51KB): fused update ----------------
__global__ __launch_bounds__(256, 2) void k3_mfma(
        const ushort_t* __restrict__ Wvp, const ushort_t* __restrict__ W1p,
        const ushort_t* __restrict__ W2p,
        const float* __restrict__ bm1, const float* __restrict__ bm2,
        float* __restrict__ out, int n_nodes) {
    // pool layout (bytes):
    //  Ab  @0      : v_mid bf16 48x136            = 13056   (phase0 -> final)
    //  vlb @13056  : v_l  bf16 48x136             = 13056   (gemm1 -> final)
    //  vrc @26112  : v_r  bf16 48x136             = 13056   (gemm1 -> phase2)
    //  Tb  @39168  : ts   bf16 16x264             =  8448   (phase2 -> gemm2)
    //  Hb  @47616  : h1   bf16 16x136             =  4352   (gemm2 -> gemm3)
    //  C3 f32 [16][400] overlays @26112..51712 (vrc+Tb+Hb, all dead by epilogue)
    __shared__ __align__(16) char pool[51968];
    ushort_t* Ab  = (ushort_t*)pool;
    ushort_t* vlb = (ushort_t*)(pool + 13056);
    ushort_t* vrc = (ushort_t*)(pool + 26112);
    ushort_t* Tb  = (ushort_t*)(pool + 39168);
    ushort_t* Hb  = (ushort_t*)(pool + 47616);
    float* C3 = (float*)(pool + 26112);   // [16][400]

    int t = threadIdx.x;
    int node0 = blockIdx.x * 16;
    int wv = t >> 6, lane = t & 63;
    int g = lane >> 4, cl = lane & 15;

    float smid_reg[8], dot_reg[8];

    // phase 0: stage v_mid bf16; s_mid -> registers
    #pragma unroll
    for (int i = 0; i < 24; ++i) {
        int flat = t + i * 256;
        int row = flat >> 7, k = flat & 127;
        int n = row / 3, d = row - n * 3;
        int node = node0 + n; if (node >= n_nodes) node = n_nodes - 1;
        Ab[row * 136 + k] = bfround(out[(size_t)node * 512 + 128 + d * 128 + k]);
    }
    #pragma unroll
    for (int i = 0; i < 8; ++i) {
        int flat = t + i * 256;
        int n = flat >> 7, k = flat & 127;
        int node = node0 + n; if (node >= n_nodes) node = n_nodes - 1;
        smid_reg[i] = out[(size_t)node * 512 + k];
    }
    __syncthreads();

    // GEMM1: (48x128)@(128x256) -> v_l | v_r
    #pragma unroll
    for (int rt = 0; rt < 3; ++rt) {
        bf16x8 ah[4];
        #pragma unroll
        for (int ks = 0; ks < 4; ++ks)
            ah[ks] = *(const bf16x8*)&Ab[(rt * 16 + cl) * 136 + ks * 32 + g * 8];
        f32x4 acc[4] = {};
        #pragma unroll
        for (int ks = 0; ks < 4; ++ks) {
            #pragma unroll
            for (int c = 0; c < 4; ++c) {
                int ct = wv * 4 + c;
                bf16x8 bh = *(const bf16x8*)&Wvp[((size_t)(ks * 16 + ct) * 64 + lane) * 8];
                acc[c] = __builtin_amdgcn_mfma_f32_16x16x32_bf16(ah[ks], bh, acc[c], 0, 0, 0);
            }
        }
        #pragma unroll
        for (int c = 0; c < 4; ++c) {
            int col = (wv * 4 + c) * 16 + cl;
            ushort_t* dst = (col < 128) ? vlb : vrc;
            int cc = col & 127;
            #pragma unroll
            for (int r = 0; r < 4; ++r)
                dst[(rt * 16 + g * 4 + r) * 136 + cc] = bfround(acc[c][r]);
        }
    }
    __syncthreads();

    // phase 2: v_norm, dot -> regs; build ts
    #pragma unroll
    for (int i = 0; i < 8; ++i) {
        int flat = t + i * 256;
        int n = flat >> 7, h = flat & 127;
        float r0 = bfu(vrc[(3 * n + 0) * 136 + h]);
        float r1 = bfu(vrc[(3 * n + 1) * 136 + h]);
        float r2 = bfu(vrc[(3 * n + 2) * 136 + h]);
        float l0 = bfu(vlb[(3 * n + 0) * 136 + h]);
        float l1 = bfu(vlb[(3 * n + 1) * 136 + h]);
        float l2 = bfu(vlb[(3 * n + 2) * 136 + h]);
        float nrm = sqrtf(r0 * r0 + r1 * r1 + r2 * r2 + NEPS);
        dot_reg[i] = r0 * l0 + r1 * l1 + r2 * l2;
        Tb[n * 264 + 128 + h] = bfround(nrm);
        Tb[n * 264 + h] = bfround(smid_reg[i]);
    }
    __syncthreads();

    // GEMM2: (16x256)@(256x128) + bm1 -> silu -> h1
    f32x4 acc2[2] = {};
    #pragma unroll
    for (int ks = 0; ks < 8; ++ks) {
        bf16x8 ah = *(const bf16x8*)&Tb[cl * 264 + ks * 32 + g * 8];
        #pragma unroll
        for (int c = 0; c < 2; ++c) {
            int ct = wv * 2 + c;
            bf16x8 bh = *(const bf16x8*)&W1p[((size_t)(ks * 8 + ct) * 64 + lane) * 8];
            acc2[c] = __builtin_amdgcn_mfma_f32_16x16x32_bf16(ah, bh, acc2[c], 0, 0, 0);
        }
    }
    #pragma unroll
    for (int c = 0; c < 2; ++c) {
        int col = (wv * 2 + c) * 16 + cl;
        float bias = bm1[col];
        #pragma unroll
        for (int r = 0; r < 4; ++r) {
            int row = g * 4 + r;
            Hb[row * 136 + col] = bfround(silu_f(acc2[c][r] + bias));
        }
    }
    __syncthreads();

    // GEMM3: (16x128)@(128x384) + bm2 -> C3 (overlay)
    f32x4 acc3[6] = {};
    #pragma unroll
    for (int ks = 0; ks < 4; ++ks) {
        bf16x8 ah = *(const bf16x8*)&Hb[cl * 136 + ks * 32 + g * 8];
        #pragma unroll
        for (int c = 0; c < 6; ++c) {
            int ct = wv * 6 + c;
            bf16x8 bh = *(const bf16x8*)&W2p[((size_t)(ks * 24 + ct) * 64 + lane) * 8];
            acc3[c] = __builtin_amdgcn_mfma_f32_16x16x32_bf16(ah, bh, acc3[c], 0, 0, 0);
        }
    }
    __syncthreads();   // vrc/Tb/Hb reads done before overlay write
    #pragma unroll
    for (int c = 0; c < 6; ++c) {
        int col = (wv * 6 + c) * 16 + cl;
        float bias = bm2[col];
        #pragma unroll
        for (int r = 0; r < 4; ++r)
            C3[(g * 4 + r) * 400 + col] = acc3[c][r] + bias;
    }
    __syncthreads();

    // final combine
    #pragma unroll
    for (int i = 0; i < 8; ++i) {
        int flat = t + i * 256;
        int n = flat >> 7, h = flat & 127;
        int node = node0 + n;
        if (node >= n_nodes) continue;
        float ds_u = C3[n * 400 + h];
        float dv_u = C3[n * 400 + 128 + h];
        float dsv  = C3[n * 400 + 256 + h] * dot_reg[i];
        out[(size_t)node * 512 + h] = (smid_reg[i] + ds_u + dsv) * EPSILON;
        #pragma unroll
        for (int d = 0; d < 3; ++d) {
            int row = 3 * n + d;
            float vmid = bfu(Ab[row * 136 + h]);
            float vl_v = bfu(vlb[row * 136 + h]);
            out[(size_t)node * 512 + 128 + d * 128 + h] = (vmid + vl_v * dv_u) * EPSILON;
        }
    }
}

static inline size_t align_up(size_t x, size_t a) { return (x + a - 1) / a * a; }

extern "C" void kernel_launch(void* const* d_in, const int* in_sizes, int n_in,
                              void* d_out, int out_size, void* d_ws, size_t ws_size,
                              hipStream_t stream) {
    const float* s       = (const float*)d_in[0];
    const float* v       = (const float*)d_in[1];
    const float* dir     = (const float*)d_in[2];
    const float* Wij     = (const float*)d_in[3];
    const int*   senders = (const int*)d_in[4];
    const int*   recv    = (const int*)d_in[5];
    const float* Wi1     = (const float*)d_in[6];
    const float* bi1     = (const float*)d_in[7];
    const float* Wi2     = (const float*)d_in[8];
    const float* bi2     = (const float*)d_in[9];
    const float* Wm1     = (const float*)d_in[10];
    const float* bm1     = (const float*)d_in[11];
    const float* Wm2     = (const float*)d_in[12];
    const float* bm2     = (const float*)d_in[13];
    const float* Wvm     = (const float*)d_in[14];

    int n_nodes = in_sizes[0] / H;
    int n_edges = in_sizes[4];
    float* out = (float*)d_out;

    // workspace layout
    char* ws = (char*)d_ws;
    size_t off = 0;
    ushort_t* x   = (ushort_t*)(ws + off); off = align_up(off + (size_t)n_nodes * 384 * 2, 256);
    ushort_t* vbf = (ushort_t*)(ws + off); off = align_up(off + (size_t)n_nodes * 384 * 2, 256);
    int* starts = (int*)(ws + off); off = align_up(off + (size_t)n_nodes * 4, 256);
    int* cnt    = (int*)(ws + off); off = align_up(off + (size_t)(n_nodes + 1) * 4, 256);
    int* cursor = cnt + n_nodes;
    int* head   = (int*)(ws + off); off = align_up(off + (size_t)n_nodes * 4, 256);
    int* eord   = (int*)(ws + off); off = align_up(off + (size_t)n_edges * 4, 256);
    int* erecv  = (int*)(ws + off); off = align_up(off + (size_t)n_edges * 4, 256);
    ushort_t* Wi1p = (ushort_t*)(ws + off); off = align_up(off + 16384 * 2, 256);
    ushort_t* Wi2p = (ushort_t*)(ws + off); off = align_up(off + 49152 * 2, 256);
    ushort_t* Wvp  = (ushort_t*)(ws + off); off = align_up(off + 32768 * 2, 256);
    ushort_t* Wm1p = (ushort_t*)(ws + off); off = align_up(off + 32768 * 2, 256);
    ushort_t* Wm2p = (ushort_t*)(ws + off); off = align_up(off + 49152 * 2, 256);
    if (off > ws_size) return;   // ws is ~3.6 GB; always fits

    // CSR build
    hipMemsetAsync(cnt, 0, (size_t)(n_nodes + 1) * 4, stream);
    k_hist<<<(n_edges + 255) / 256, 256, 0, stream>>>(senders, cnt, n_edges);
    k_alloc<<<(n_nodes + 255) / 256, 256, 0, stream>>>(cnt, starts, head, cursor, n_nodes);
    k_scatter<<<(n_edges + 255) / 256, 256, 0, stream>>>(senders, recv, head, eord, erecv, n_edges);

    // weight packs + input conversions
    k_pack<<<(128 * 128 + 255) / 256, 256, 0, stream>>>(Wi1, 128, 128, Wi1p);
    k_pack<<<(128 * 384 + 255) / 256, 256, 0, stream>>>(Wi2, 128, 384, Wi2p);
    k_pack<<<(128 * 256 + 255) / 256, 256, 0, stream>>>(Wvm, 128, 256, Wvp);
    k_pack<<<(256 * 128 + 255) / 256, 256, 0, stream>>>(Wm1, 256, 128, Wm1p);
    k_pack<<<(128 * 384 + 255) / 256, 256, 0, stream>>>(Wm2, 128, 384, Wm2p);
    int n4 = n_nodes * 96;
    k_cvt_v<<<(n4 + 255) / 256, 256, 0, stream>>>((const float4*)v, (ushort4*)vbf, n4);

    k1_mfma<<<(n_nodes + 15) / 16, 256, 0, stream>>>(
        s, Wi1p, Wi2p, bi1, bi2, x, n_nodes);

    k2_csr2<<<n_nodes, 256, 0, stream>>>(
        (const float4*)s, (const float4*)v, vbf, x, dir,
        (const float4*)Wij, starts, cnt, eord, erecv, (float4*)out, n_nodes);

    k3_mfma<<<(n_nodes + 15) / 16, 256, 0, stream>>>(
        Wvp, Wm1p, Wm2p, bm1, bm2, out, n_nodes);
}

// Round 6
// 483.213 us; speedup vs baseline: 3.9921x; 1.0914x over previous
//
#include <hip/hip_runtime.h>

#define H 128
#define EPSILON 0.7071067811865476f
#define NEPS 1e-8f

typedef short bf16x8 __attribute__((ext_vector_type(8)));
typedef float f32x4 __attribute__((ext_vector_type(4)));
typedef unsigned short ushort_t;

__device__ __forceinline__ float silu_f(float x) {
    return x / (1.0f + __expf(-x));
}
__device__ __forceinline__ unsigned short bfround(float w) {
    unsigned ub = __float_as_uint(w);
    return (unsigned short)((ub + 0x7FFF + ((ub >> 16) & 1)) >> 16);
}
__device__ __forceinline__ float bfu(unsigned short u) { return __uint_as_float(((unsigned)u) << 16); }

// pack one element of a K x N weight into fragment-major bf16
// elem (ks, ct, lane, j) at ((ks*CT+ct)*64+lane)*8+j = W[ks*32+(lane>>4)*8+j][ct*16+(lane&15)]
__device__ __forceinline__ void pack_one(const float* __restrict__ W, int N,
                                         ushort_t* __restrict__ p, int tid) {
    int CT = N >> 4;
    int j = tid & 7;
    int l = (tid >> 3) & 63;
    int rest = tid >> 9;
    int ct = rest % CT;
    int ks = rest / CT;
    int row = ks * 32 + ((l >> 4) << 3) + j;
    int col = ct * 16 + (l & 15);
    p[tid] = bfround(W[(size_t)row * N + col]);
}

// ---------------- K_prep: zero cnt + pack 5 weights + convert v -> bf16 (ONE launch) ----------------
__global__ void k_prep(const float* __restrict__ Wi1, const float* __restrict__ Wi2,
                       const float* __restrict__ Wvm, const float* __restrict__ Wm1,
                       const float* __restrict__ Wm2,
                       ushort_t* __restrict__ Wi1p, ushort_t* __restrict__ Wi2p,
                       ushort_t* __restrict__ Wvp, ushort_t* __restrict__ Wm1p,
                       ushort_t* __restrict__ Wm2p,
                       const float4* __restrict__ v4, ushort4* __restrict__ vb,
                       int* __restrict__ cnt, int n_cnt, int n4) {
    int gid = blockIdx.x * blockDim.x + threadIdx.x;
    int stride = gridDim.x * blockDim.x;
    int S0 = n_cnt;
    int S1 = S0 + 16384;
    int S2 = S1 + 49152;
    int S3 = S2 + 32768;
    int S4 = S3 + 32768;
    int S5 = S4 + 49152;
    int S6 = S5 + n4;
    for (int i = gid; i < S6; i += stride) {
        if (i < S0)      cnt[i] = 0;
        else if (i < S1) pack_one(Wi1, 128, Wi1p, i - S0);
        else if (i < S2) pack_one(Wi2, 384, Wi2p, i - S1);
        else if (i < S3) pack_one(Wvm, 256, Wvp,  i - S2);
        else if (i < S4) pack_one(Wm1, 128, Wm1p, i - S3);
        else if (i < S5) pack_one(Wm2, 384, Wm2p, i - S4);
        else {
            int j = i - S5;
            float4 f = v4[j];
            ushort4 u;
            u.x = bfround(f.x); u.y = bfround(f.y); u.z = bfround(f.z); u.w = bfround(f.w);
            vb[j] = u;
        }
    }
}

// ---------------- K1 (MFMA): x = silu(s@Wi1+bi1)@Wi2+bi2 -> bf16 x, 16 nodes/block ----------------
__global__ __launch_bounds__(256, 4) void k1_mfma(
        const float* __restrict__ s,
        const ushort_t* __restrict__ W1p, const ushort_t* __restrict__ W2p,
        const float* __restrict__ bi1, const float* __restrict__ bi2,
        ushort_t* __restrict__ x, int n_nodes) {
    __shared__ ushort_t Ab[16 * 136];
    __shared__ ushort_t Hb[16 * 136];
    int t = threadIdx.x;
    int node0 = blockIdx.x * 16;
    int wv = t >> 6, lane = t & 63;
    int g = lane >> 4, cl = lane & 15;

    #pragma unroll
    for (int i = 0; i < 8; ++i) {
        int flat = t + i * 256;
        int n = flat >> 7, k = flat & 127;
        int node = node0 + n; if (node >= n_nodes) node = n_nodes - 1;
        Ab[n * 136 + k] = bfround(s[(size_t)node * 128 + k]);
    }
    __syncthreads();

    f32x4 acc1[2] = {};
    #pragma unroll
    for (int ks = 0; ks < 4; ++ks) {
        bf16x8 ah = *(const bf16x8*)&Ab[cl * 136 + ks * 32 + g * 8];
        #pragma unroll
        for (int c = 0; c < 2; ++c) {
            int ct = wv * 2 + c;
            bf16x8 bh = *(const bf16x8*)&W1p[((size_t)(ks * 8 + ct) * 64 + lane) * 8];
            acc1[c] = __builtin_amdgcn_mfma_f32_16x16x32_bf16(ah, bh, acc1[c], 0, 0, 0);
        }
    }
    #pragma unroll
    for (int c = 0; c < 2; ++c) {
        int col = (wv * 2 + c) * 16 + cl;
        float bias = bi1[col];
        #pragma unroll
        for (int r = 0; r < 4; ++r) {
            int row = g * 4 + r;
            Hb[row * 136 + col] = bfround(silu_f(acc1[c][r] + bias));
        }
    }
    __syncthreads();

    f32x4 acc2[6] = {};
    #pragma unroll
    for (int ks = 0; ks < 4; ++ks) {
        bf16x8 ah = *(const bf16x8*)&Hb[cl * 136 + ks * 32 + g * 8];
        #pragma unroll
        for (int c = 0; c < 6; ++c) {
            int ct = wv * 6 + c;
            bf16x8 bh = *(const bf16x8*)&W2p[((size_t)(ks * 24 + ct) * 64 + lane) * 8];
            acc2[c] = __builtin_amdgcn_mfma_f32_16x16x32_bf16(ah, bh, acc2[c], 0, 0, 0);
        }
    }
    #pragma unroll
    for (int c = 0; c < 6; ++c) {
        int col = (wv * 6 + c) * 16 + cl;
        float bias = bi2[col];
        #pragma unroll
        for (int r = 0; r < 4; ++r) {
            int node = node0 + g * 4 + r;
            if (node < n_nodes) x[(size_t)node * 384 + col] = bfround(acc2[c][r] + bias);
        }
    }
}

// ---------------- CSR build ----------------
__global__ void k_hist(const int* __restrict__ senders, int* __restrict__ cnt, int n_edges) {
    int e = blockIdx.x * blockDim.x + threadIdx.x;
    if (e < n_edges) atomicAdd(&cnt[senders[e]], 1);
}

__global__ void k_alloc(const int* __restrict__ cnt, int* __restrict__ starts,
                        int* __restrict__ head, int* __restrict__ cursor, int n) {
    int i = blockIdx.x * blockDim.x + threadIdx.x;
    int lane = threadIdx.x & 63;
    int c = (i < n) ? cnt[i] : 0;
    int pref = c;
    #pragma unroll
    for (int off = 1; off < 64; off <<= 1) {
        int up = __shfl_up(pref, off, 64);
        if (lane >= off) pref += up;
    }
    int total = __shfl(pref, 63, 64);
    int base = 0;
    if (lane == 63) base = atomicAdd(cursor, total);
    base = __shfl(base, 63, 64);
    if (i < n) { int p = base + pref - c; starts[i] = p; head[i] = p; }
}

__global__ void k_scatter(const int* __restrict__ senders, const int* __restrict__ receivers,
                          int* __restrict__ head, int* __restrict__ eord,
                          int* __restrict__ erecv, int n_edges) {
    int e = blockIdx.x * blockDim.x + threadIdx.x;
    if (e < n_edges) {
        int p = atomicAdd(&head[senders[e]], 1);
        eord[p] = e;
        erecv[p] = receivers[e];
    }
}

// ---------------- K2 (CSR): per-node gather-accumulate -> bf16 mid ----------------
__global__ __launch_bounds__(256) void k2_csr3(
        const float4* __restrict__ s4, const ushort_t* __restrict__ vbf,
        const ushort_t* __restrict__ xbf, const float* __restrict__ dir,
        const float4* __restrict__ w4, const int* __restrict__ starts,
        const int* __restrict__ cnt, const int* __restrict__ eord,
        const int* __restrict__ erecv, ushort_t* __restrict__ mid, int n_nodes) {
    __shared__ float4 red[8][128];
    int node = blockIdx.x;
    int t = threadIdx.x;
    int slot = t >> 5, lane = t & 31;
    int beg = starts[node], num = cnt[node];
    float4 ds  = {0.f, 0.f, 0.f, 0.f};
    float4 dv0 = {0.f, 0.f, 0.f, 0.f};
    float4 dv1 = {0.f, 0.f, 0.f, 0.f};
    float4 dv2 = {0.f, 0.f, 0.f, 0.f};
    for (int q = slot; q < num; q += 8) {
        int e = eord[beg + q];
        int r = erecv[beg + q];
        const float4*   we = w4  + (size_t)e * 96;
        const ushort_t* xr = xbf + (size_t)r * 384;
        const ushort_t* vr = vbf + (size_t)r * 384;
        float4 wa = we[lane], wb = we[32 + lane], wc = we[64 + lane];
        ushort4 xa = *(const ushort4*)&xr[4 * lane];
        ushort4 xb = *(const ushort4*)&xr[128 + 4 * lane];
        ushort4 xc = *(const ushort4*)&xr[256 + 4 * lane];
        ushort4 va = *(const ushort4*)&vr[4 * lane];
        ushort4 vb = *(const ushort4*)&vr[128 + 4 * lane];
        ushort4 vc = *(const ushort4*)&vr[256 + 4 * lane];
        float d0 = dir[3 * (size_t)e + 0];
        float d1 = dir[3 * (size_t)e + 1];
        float d2 = dir[3 * (size_t)e + 2];
        float bx = wb.x * bfu(xb.x), by = wb.y * bfu(xb.y), bz = wb.z * bfu(xb.z), bw = wb.w * bfu(xb.w);
        float cx = wc.x * bfu(xc.x), cy = wc.y * bfu(xc.y), cz = wc.z * bfu(xc.z), cw = wc.w * bfu(xc.w);
        ds.x += wa.x * bfu(xa.x); ds.y += wa.y * bfu(xa.y);
        ds.z += wa.z * bfu(xa.z); ds.w += wa.w * bfu(xa.w);
        dv0.x += bx * d0 + cx * bfu(va.x); dv0.y += by * d0 + cy * bfu(va.y);
        dv0.z += bz * d0 + cz * bfu(va.z); dv0.w += bw * d0 + cw * bfu(va.w);
        dv1.x += bx * d1 + cx * bfu(vb.x); dv1.y += by * d1 + cy * bfu(vb.y);
        dv1.z += bz * d1 + cz * bfu(vb.z); dv1.w += bw * d1 + cw * bfu(vb.w);
        dv2.x += bx * d2 + cx * bfu(vc.x); dv2.y += by * d2 + cy * bfu(vc.y);
        dv2.z += bz * d2 + cz * bfu(vc.z); dv2.w += bw * d2 + cw * bfu(vc.w);
    }
    red[slot][lane]      = ds;
    red[slot][32 + lane] = dv0;
    red[slot][64 + lane] = dv1;
    red[slot][96 + lane] = dv2;
    __syncthreads();
    if (t < 128) {
        float4 acc = red[0][t];
        #pragma unroll
        for (int q2 = 1; q2 < 8; ++q2) {
            float4 r2 = red[q2][t];
            acc.x += r2.x; acc.y += r2.y; acc.z += r2.z; acc.w += r2.w;
        }
        int which = t >> 5, hh = t & 31;
        float4 base;
        if (which == 0) {
            base = s4[(size_t)node * 32 + hh];
        } else {
            ushort4 u = *(const ushort4*)&vbf[(size_t)node * 384 + (size_t)(which - 1) * 128 + 4 * hh];
            base.x = bfu(u.x); base.y = bfu(u.y); base.z = bfu(u.z); base.w = bfu(u.w);
        }
        ushort4 o;
        o.x = bfround((base.x + acc.x) * EPSILON);
        o.y = bfround((base.y + acc.y) * EPSILON);
        o.z = bfround((base.z + acc.z) * EPSILON);
        o.w = bfround((base.w + acc.w) * EPSILON);
        *(ushort4*)&mid[(size_t)node * 512 + 4 * t] = o;
    }
}

// ---------------- K3 (MFMA): fused update; reads bf16 mid, writes fp32 out ----------------
__global__ __launch_bounds__(256, 2) void k3_mfma(
        const ushort_t* __restrict__ mid,
        const ushort_t* __restrict__ Wvp, const ushort_t* __restrict__ W1p,
        const ushort_t* __restrict__ W2p,
        const float* __restrict__ bm1, const float* __restrict__ bm2,
        float* __restrict__ out, int n_nodes) {
    // pool layout (bytes):
    //  Ab  @0      : v_mid bf16 48x136 = 13056   (phase0 -> final)
    //  vlb @13056  : v_l  bf16 48x136  = 13056   (gemm1 -> final)
    //  vrc @26112  : v_r  bf16 48x136  = 13056   (gemm1 -> phase2)
    //  Tb  @39168  : ts   bf16 16x264  =  8448   (phase2 -> gemm2)
    //  Hb  @47616  : h1   bf16 16x136  =  4352   (gemm2 -> gemm3)
    //  C3 f32 [16][400] overlays @26112..51712
    __shared__ __align__(16) char pool[51968];
    ushort_t* Ab  = (ushort_t*)pool;
    ushort_t* vlb = (ushort_t*)(pool + 13056);
    ushort_t* vrc = (ushort_t*)(pool + 26112);
    ushort_t* Tb  = (ushort_t*)(pool + 39168);
    ushort_t* Hb  = (ushort_t*)(pool + 47616);
    float* C3 = (float*)(pool + 26112);   // [16][400]

    int t = threadIdx.x;
    int node0 = blockIdx.x * 16;
    int wv = t >> 6, lane = t & 63;
    int g = lane >> 4, cl = lane & 15;

    float smid_reg[8], dot_reg[8];

    // phase 0: stage v_mid (48x128 bf16) via ushort4; s_mid -> registers
    #pragma unroll
    for (int i = 0; i < 6; ++i) {
        int flat4 = t + i * 256;          // ushort4 index over 48*32
        int row = flat4 >> 5, k4 = flat4 & 31;
        int n = row / 3, d = row - n * 3;
        int node = node0 + n; if (node >= n_nodes) node = n_nodes - 1;
        ushort4 u = *(const ushort4*)&mid[(size_t)node * 512 + (size_t)(1 + d) * 128 + 4 * k4];
        *(ushort4*)&Ab[row * 136 + 4 * k4] = u;
    }
    #pragma unroll
    for (int i = 0; i < 8; ++i) {
        int flat = t + i * 256;
        int n = flat >> 7, k = flat & 127;
        int node = node0 + n; if (node >= n_nodes) node = n_nodes - 1;
        smid_reg[i] = bfu(mid[(size_t)node * 512 + k]);
    }
    __syncthreads();

    // GEMM1: (48x128)@(128x256) -> v_l | v_r
    #pragma unroll
    for (int rt = 0; rt < 3; ++rt) {
        bf16x8 ah[4];
        #pragma unroll
        for (int ks = 0; ks < 4; ++ks)
            ah[ks] = *(const bf16x8*)&Ab[(rt * 16 + cl) * 136 + ks * 32 + g * 8];
        f32x4 acc[4] = {};
        #pragma unroll
        for (int ks = 0; ks < 4; ++ks) {
            #pragma unroll
            for (int c = 0; c < 4; ++c) {
                int ct = wv * 4 + c;
                bf16x8 bh = *(const bf16x8*)&Wvp[((size_t)(ks * 16 + ct) * 64 + lane) * 8];
                acc[c] = __builtin_amdgcn_mfma_f32_16x16x32_bf16(ah[ks], bh, acc[c], 0, 0, 0);
            }
        }
        #pragma unroll
        for (int c = 0; c < 4; ++c) {
            int col = (wv * 4 + c) * 16 + cl;
            ushort_t* dst = (col < 128) ? vlb : vrc;
            int cc = col & 127;
            #pragma unroll
            for (int r = 0; r < 4; ++r)
                dst[(rt * 16 + g * 4 + r) * 136 + cc] = bfround(acc[c][r]);
        }
    }
    __syncthreads();

    // phase 2: v_norm, dot -> regs; build ts
    #pragma unroll
    for (int i = 0; i < 8; ++i) {
        int flat = t + i * 256;
        int n = flat >> 7, h = flat & 127;
        float r0 = bfu(vrc[(3 * n + 0) * 136 + h]);
        float r1 = bfu(vrc[(3 * n + 1) * 136 + h]);
        float r2 = bfu(vrc[(3 * n + 2) * 136 + h]);
        float l0 = bfu(vlb[(3 * n + 0) * 136 + h]);
        float l1 = bfu(vlb[(3 * n + 1) * 136 + h]);
        float l2 = bfu(vlb[(3 * n + 2) * 136 + h]);
        float nrm = sqrtf(r0 * r0 + r1 * r1 + r2 * r2 + NEPS);
        dot_reg[i] = r0 * l0 + r1 * l1 + r2 * l2;
        Tb[n * 264 + 128 + h] = bfround(nrm);
        Tb[n * 264 + h] = bfround(smid_reg[i]);
    }
    __syncthreads();

    // GEMM2: (16x256)@(256x128) + bm1 -> silu -> h1
    f32x4 acc2[2] = {};
    #pragma unroll
    for (int ks = 0; ks < 8; ++ks) {
        bf16x8 ah = *(const bf16x8*)&Tb[cl * 264 + ks * 32 + g * 8];
        #pragma unroll
        for (int c = 0; c < 2; ++c) {
            int ct = wv * 2 + c;
            bf16x8 bh = *(const bf16x8*)&W1p[((size_t)(ks * 8 + ct) * 64 + lane) * 8];
            acc2[c] = __builtin_amdgcn_mfma_f32_16x16x32_bf16(ah, bh, acc2[c], 0, 0, 0);
        }
    }
    #pragma unroll
    for (int c = 0; c < 2; ++c) {
        int col = (wv * 2 + c) * 16 + cl;
        float bias = bm1[col];
        #pragma unroll
        for (int r = 0; r < 4; ++r) {
            int row = g * 4 + r;
            Hb[row * 136 + col] = bfround(silu_f(acc2[c][r] + bias));
        }
    }
    __syncthreads();

    // GEMM3: (16x128)@(128x384) + bm2 -> C3 (overlay)
    f32x4 acc3[6] = {};
    #pragma unroll
    for (int ks = 0; ks < 4; ++ks) {
        bf16x8 ah = *(const bf16x8*)&Hb[cl * 136 + ks * 32 + g * 8];
        #pragma unroll
        for (int c = 0; c < 6; ++c) {
            int ct = wv * 6 + c;
            bf16x8 bh = *(const bf16x8*)&W2p[((size_t)(ks * 24 + ct) * 64 + lane) * 8];
            acc3[c] = __builtin_amdgcn_mfma_f32_16x16x32_bf16(ah, bh, acc3[c], 0, 0, 0);
        }
    }
    __syncthreads();   // vrc/Tb/Hb reads done before overlay write
    #pragma unroll
    for (int c = 0; c < 6; ++c) {
        int col = (wv * 6 + c) * 16 + cl;
        float bias = bm2[col];
        #pragma unroll
        for (int r = 0; r < 4; ++r)
            C3[(g * 4 + r) * 400 + col] = acc3[c][r] + bias;
    }
    __syncthreads();

    // final combine
    #pragma unroll
    for (int i = 0; i < 8; ++i) {
        int flat = t + i * 256;
        int n = flat >> 7, h = flat & 127;
        int node = node0 + n;
        if (node >= n_nodes) continue;
        float ds_u = C3[n * 400 + h];
        float dv_u = C3[n * 400 + 128 + h];
        float dsv  = C3[n * 400 + 256 + h] * dot_reg[i];
        out[(size_t)node * 512 + h] = (smid_reg[i] + ds_u + dsv) * EPSILON;
        #pragma unroll
        for (int d = 0; d < 3; ++d) {
            int row = 3 * n + d;
            float vmid = bfu(Ab[row * 136 + h]);
            float vl_v = bfu(vlb[row * 136 + h]);
            out[(size_t)node * 512 + 128 + d * 128 + h] = (vmid + vl_v * dv_u) * EPSILON;
        }
    }
}

static inline size_t align_up(size_t x, size_t a) { return (x + a - 1) / a * a; }

extern "C" void kernel_launch(void* const* d_in, const int* in_sizes, int n_in,
                              void* d_out, int out_size, void* d_ws, size_t ws_size,
                              hipStream_t stream) {
    const float* s       = (const float*)d_in[0];
    const float* v       = (const float*)d_in[1];
    const float* dir     = (const float*)d_in[2];
    const float* Wij     = (const float*)d_in[3];
    const int*   senders = (const int*)d_in[4];
    const int*   recv    = (const int*)d_in[5];
    const float* Wi1     = (const float*)d_in[6];
    const float* bi1     = (const float*)d_in[7];
    const float* Wi2     = (const float*)d_in[8];
    const float* bi2     = (const float*)d_in[9];
    const float* Wm1     = (const float*)d_in[10];
    const float* bm1     = (const float*)d_in[11];
    const float* Wm2     = (const float*)d_in[12];
    const float* bm2     = (const float*)d_in[13];
    const float* Wvm     = (const float*)d_in[14];

    int n_nodes = in_sizes[0] / H;
    int n_edges = in_sizes[4];
    float* out = (float*)d_out;

    // workspace layout
    char* ws = (char*)d_ws;
    size_t off = 0;
    ushort_t* x   = (ushort_t*)(ws + off); off = align_up(off + (size_t)n_nodes * 384 * 2, 256);
    ushort_t* vbf = (ushort_t*)(ws + off); off = align_up(off + (size_t)n_nodes * 384 * 2, 256);
    ushort_t* mid = (ushort_t*)(ws + off); off = align_up(off + (size_t)n_nodes * 512 * 2, 256);
    int* starts = (int*)(ws + off); off = align_up(off + (size_t)n_nodes * 4, 256);
    int* cnt    = (int*)(ws + off); off = align_up(off + (size_t)(n_nodes + 1) * 4, 256);
    int* cursor = cnt + n_nodes;
    int* head   = (int*)(ws + off); off = align_up(off + (size_t)n_nodes * 4, 256);
    int* eord   = (int*)(ws + off); off = align_up(off + (size_t)n_edges * 4, 256);
    int* erecv  = (int*)(ws + off); off = align_up(off + (size_t)n_edges * 4, 256);
    ushort_t* Wi1p = (ushort_t*)(ws + off); off = align_up(off + 16384 * 2, 256);
    ushort_t* Wi2p = (ushort_t*)(ws + off); off = align_up(off + 49152 * 2, 256);
    ushort_t* Wvp  = (ushort_t*)(ws + off); off = align_up(off + 32768 * 2, 256);
    ushort_t* Wm1p = (ushort_t*)(ws + off); off = align_up(off + 32768 * 2, 256);
    ushort_t* Wm2p = (ushort_t*)(ws + off); off = align_up(off + 49152 * 2, 256);
    if (off > ws_size) return;   // ws is ~3.6 GB; always fits

    // prep: zero cnt+cursor, pack weights, convert v (one launch)
    int n4 = n_nodes * 96;
    int prep_total = (n_nodes + 1) + 16384 + 49152 + 32768 + 32768 + 49152 + n4;
    int prep_blocks = (prep_total + 255) / 256;
    if (prep_blocks > 2048) prep_blocks = 2048;
    k_prep<<<prep_blocks, 256, 0, stream>>>(
        Wi1, Wi2, Wvm, Wm1, Wm2, Wi1p, Wi2p, Wvp, Wm1p, Wm2p,
        (const float4*)v, (ushort4*)vbf, cnt, n_nodes + 1, n4);

    // CSR build
    k_hist<<<(n_edges + 255) / 256, 256, 0, stream>>>(senders, cnt, n_edges);
    k_alloc<<<(n_nodes + 255) / 256, 256, 0, stream>>>(cnt, starts, head, cursor, n_nodes);
    k_scatter<<<(n_edges + 255) / 256, 256, 0, stream>>>(senders, recv, head, eord, erecv, n_edges);

    k1_mfma<<<(n_nodes + 15) / 16, 256, 0, stream>>>(
        s, Wi1p, Wi2p, bi1, bi2, x, n_nodes);

    k2_csr3<<<n_nodes, 256, 0, stream>>>(
        (const float4*)s, vbf, x, dir,
        (const float4*)Wij, starts, cnt, eord, erecv, mid, n_nodes);

    k3_mfma<<<(n_nodes + 15) / 16, 256, 0, stream>>>(
        mid, Wvp, Wm1p, Wm2p, bm1, bm2, out, n_nodes);
}

// Round 7
// 476.785 us; speedup vs baseline: 4.0459x; 1.0135x over previous
//
#include <hip/hip_runtime.h>

#define H 128
#define EPSILON 0.7071067811865476f
#define NEPS 1e-8f

typedef short bf16x8 __attribute__((ext_vector_type(8)));
typedef float f32x4 __attribute__((ext_vector_type(4)));
typedef unsigned short ushort_t;

__device__ __forceinline__ float silu_f(float x) {
    return x / (1.0f + __expf(-x));
}
__device__ __forceinline__ unsigned short bfround(float w) {
    unsigned ub = __float_as_uint(w);
    return (unsigned short)((ub + 0x7FFF + ((ub >> 16) & 1)) >> 16);
}
__device__ __forceinline__ float bfu(unsigned short u) { return __uint_as_float(((unsigned)u) << 16); }

// pack one element of a K x N weight into fragment-major bf16
// elem (ks, ct, lane, j) at ((ks*CT+ct)*64+lane)*8+j = W[ks*32+(lane>>4)*8+j][ct*16+(lane&15)]
__device__ __forceinline__ void pack_one(const float* __restrict__ W, int N,
                                         ushort_t* __restrict__ p, int tid) {
    int CT = N >> 4;
    int j = tid & 7;
    int l = (tid >> 3) & 63;
    int rest = tid >> 9;
    int ct = rest % CT;
    int ks = rest / CT;
    int row = ks * 32 + ((l >> 4) << 3) + j;
    int col = ct * 16 + (l & 15);
    p[tid] = bfround(W[(size_t)row * N + col]);
}

// ---------------- K_prep: zero cnt + pack 5 weights + v -> xv[.][384:768] bf16 ----------------
__global__ void k_prep(const float* __restrict__ Wi1, const float* __restrict__ Wi2,
                       const float* __restrict__ Wvm, const float* __restrict__ Wm1,
                       const float* __restrict__ Wm2,
                       ushort_t* __restrict__ Wi1p, ushort_t* __restrict__ Wi2p,
                       ushort_t* __restrict__ Wvp, ushort_t* __restrict__ Wm1p,
                       ushort_t* __restrict__ Wm2p,
                       const float4* __restrict__ v4, ushort_t* __restrict__ xv,
                       int* __restrict__ cnt, int n_cnt, int n4) {
    int gid = blockIdx.x * blockDim.x + threadIdx.x;
    int stride = gridDim.x * blockDim.x;
    int S0 = n_cnt;
    int S1 = S0 + 16384;
    int S2 = S1 + 49152;
    int S3 = S2 + 32768;
    int S4 = S3 + 32768;
    int S5 = S4 + 49152;
    int S6 = S5 + n4;
    for (int i = gid; i < S6; i += stride) {
        if (i < S0)      cnt[i] = 0;
        else if (i < S1) pack_one(Wi1, 128, Wi1p, i - S0);
        else if (i < S2) pack_one(Wi2, 384, Wi2p, i - S1);
        else if (i < S3) pack_one(Wvm, 256, Wvp,  i - S2);
        else if (i < S4) pack_one(Wm1, 128, Wm1p, i - S3);
        else if (i < S5) pack_one(Wm2, 384, Wm2p, i - S4);
        else {
            int j = i - S5;                 // float4 index over n_nodes*96
            int node = j / 96, part = j - node * 96;
            float4 f = v4[j];
            ushort4 u;
            u.x = bfround(f.x); u.y = bfround(f.y); u.z = bfround(f.z); u.w = bfround(f.w);
            *(ushort4*)&xv[(size_t)node * 768 + 384 + 4 * part] = u;
        }
    }
}

// ---------------- K1 (MFMA): x = silu(s@Wi1+bi1)@Wi2+bi2 -> xv[.][0:384], 16 nodes/block ----------------
__global__ __launch_bounds__(256, 6) void k1_mfma(
        const float* __restrict__ s,
        const ushort_t* __restrict__ W1p, const ushort_t* __restrict__ W2p,
        const float* __restrict__ bi1, const float* __restrict__ bi2,
        ushort_t* __restrict__ xv, int n_nodes) {
    __shared__ ushort_t Ab[16 * 136];
    __shared__ ushort_t Hb[16 * 136];
    int t = threadIdx.x;
    int node0 = blockIdx.x * 16;
    int wv = t >> 6, lane = t & 63;
    int g = lane >> 4, cl = lane & 15;

    #pragma unroll
    for (int i = 0; i < 8; ++i) {
        int flat = t + i * 256;
        int n = flat >> 7, k = flat & 127;
        int node = node0 + n; if (node >= n_nodes) node = n_nodes - 1;
        Ab[n * 136 + k] = bfround(s[(size_t)node * 128 + k]);
    }
    __syncthreads();

    f32x4 acc1[2] = {};
    #pragma unroll
    for (int ks = 0; ks < 4; ++ks) {
        bf16x8 ah = *(const bf16x8*)&Ab[cl * 136 + ks * 32 + g * 8];
        #pragma unroll
        for (int c = 0; c < 2; ++c) {
            int ct = wv * 2 + c;
            bf16x8 bh = *(const bf16x8*)&W1p[((size_t)(ks * 8 + ct) * 64 + lane) * 8];
            acc1[c] = __builtin_amdgcn_mfma_f32_16x16x32_bf16(ah, bh, acc1[c], 0, 0, 0);
        }
    }
    #pragma unroll
    for (int c = 0; c < 2; ++c) {
        int col = (wv * 2 + c) * 16 + cl;
        float bias = bi1[col];
        #pragma unroll
        for (int r = 0; r < 4; ++r) {
            int row = g * 4 + r;
            Hb[row * 136 + col] = bfround(silu_f(acc1[c][r] + bias));
        }
    }
    __syncthreads();

    f32x4 acc2[6] = {};
    #pragma unroll
    for (int ks = 0; ks < 4; ++ks) {
        bf16x8 ah = *(const bf16x8*)&Hb[cl * 136 + ks * 32 + g * 8];
        #pragma unroll
        for (int c = 0; c < 6; ++c) {
            int ct = wv * 6 + c;
            bf16x8 bh = *(const bf16x8*)&W2p[((size_t)(ks * 24 + ct) * 64 + lane) * 8];
            acc2[c] = __builtin_amdgcn_mfma_f32_16x16x32_bf16(ah, bh, acc2[c], 0, 0, 0);
        }
    }
    #pragma unroll
    for (int c = 0; c < 6; ++c) {
        int col = (wv * 6 + c) * 16 + cl;
        float bias = bi2[col];
        #pragma unroll
        for (int r = 0; r < 4; ++r) {
            int node = node0 + g * 4 + r;
            if (node < n_nodes) xv[(size_t)node * 768 + col] = bfround(acc2[c][r] + bias);
        }
    }
}

// ---------------- CSR build ----------------
__global__ void k_hist(const int* __restrict__ senders, int* __restrict__ cnt, int n_edges) {
    int e = blockIdx.x * blockDim.x + threadIdx.x;
    if (e < n_edges) atomicAdd(&cnt[senders[e]], 1);
}

__global__ void k_alloc(const int* __restrict__ cnt, int* __restrict__ starts,
                        int* __restrict__ head, int* __restrict__ cursor, int n) {
    int i = blockIdx.x * blockDim.x + threadIdx.x;
    int lane = threadIdx.x & 63;
    int c = (i < n) ? cnt[i] : 0;
    int pref = c;
    #pragma unroll
    for (int off = 1; off < 64; off <<= 1) {
        int up = __shfl_up(pref, off, 64);
        if (lane >= off) pref += up;
    }
    int total = __shfl(pref, 63, 64);
    int base = 0;
    if (lane == 63) base = atomicAdd(cursor, total);
    base = __shfl(base, 63, 64);
    if (i < n) { int p = base + pref - c; starts[i] = p; head[i] = p; }
}

__global__ void k_scatter(const int* __restrict__ senders, const int* __restrict__ receivers,
                          int* __restrict__ head, int2* __restrict__ epair, int n_edges) {
    int e = blockIdx.x * blockDim.x + threadIdx.x;
    if (e < n_edges) {
        int p = atomicAdd(&head[senders[e]], 1);
        int2 pr; pr.x = e; pr.y = receivers[e];
        epair[p] = pr;
    }
}

// ---------------- K2 (CSR): per-node gather-accumulate -> bf16 mid ----------------
__global__ __launch_bounds__(256) void k2_csr(
        const float4* __restrict__ s4, const ushort_t* __restrict__ xv,
        const float* __restrict__ dir, const float4* __restrict__ w4,
        const int* __restrict__ starts, const int* __restrict__ cnt,
        const int2* __restrict__ epair, ushort_t* __restrict__ mid, int n_nodes) {
    __shared__ float4 red[8][128];
    int node = blockIdx.x;
    int t = threadIdx.x;
    int slot = t >> 5, lane = t & 31;
    int beg = starts[node], num = cnt[node];
    float4 ds  = {0.f, 0.f, 0.f, 0.f};
    float4 dv0 = {0.f, 0.f, 0.f, 0.f};
    float4 dv1 = {0.f, 0.f, 0.f, 0.f};
    float4 dv2 = {0.f, 0.f, 0.f, 0.f};
    for (int q = slot; q < num; q += 8) {
        int2 er = epair[beg + q];
        int e = er.x, r = er.y;
        const float4*   we  = w4 + (size_t)e * 96;
        const ushort_t* xvr = xv + (size_t)r * 768;
        float4 wa = we[lane], wb = we[32 + lane], wc = we[64 + lane];
        ushort4 xa = *(const ushort4*)&xvr[4 * lane];
        ushort4 xb = *(const ushort4*)&xvr[128 + 4 * lane];
        ushort4 xc = *(const ushort4*)&xvr[256 + 4 * lane];
        ushort4 va = *(const ushort4*)&xvr[384 + 4 * lane];
        ushort4 vb = *(const ushort4*)&xvr[512 + 4 * lane];
        ushort4 vc = *(const ushort4*)&xvr[640 + 4 * lane];
        float d0 = dir[3 * (size_t)e + 0];
        float d1 = dir[3 * (size_t)e + 1];
        float d2 = dir[3 * (size_t)e + 2];
        float bx = wb.x * bfu(xb.x), by = wb.y * bfu(xb.y), bz = wb.z * bfu(xb.z), bw = wb.w * bfu(xb.w);
        float cx = wc.x * bfu(xc.x), cy = wc.y * bfu(xc.y), cz = wc.z * bfu(xc.z), cw = wc.w * bfu(xc.w);
        ds.x += wa.x * bfu(xa.x); ds.y += wa.y * bfu(xa.y);
        ds.z += wa.z * bfu(xa.z); ds.w += wa.w * bfu(xa.w);
        dv0.x += bx * d0 + cx * bfu(va.x); dv0.y += by * d0 + cy * bfu(va.y);
        dv0.z += bz * d0 + cz * bfu(va.z); dv0.w += bw * d0 + cw * bfu(va.w);
        dv1.x += bx * d1 + cx * bfu(vb.x); dv1.y += by * d1 + cy * bfu(vb.y);
        dv1.z += bz * d1 + cz * bfu(vb.z); dv1.w += bw * d1 + cw * bfu(vb.w);
        dv2.x += bx * d2 + cx * bfu(vc.x); dv2.y += by * d2 + cy * bfu(vc.y);
        dv2.z += bz * d2 + cz * bfu(vc.z); dv2.w += bw * d2 + cw * bfu(vc.w);
    }
    red[slot][lane]      = ds;
    red[slot][32 + lane] = dv0;
    red[slot][64 + lane] = dv1;
    red[slot][96 + lane] = dv2;
    __syncthreads();
    if (t < 128) {
        float4 acc = red[0][t];
        #pragma unroll
        for (int q2 = 1; q2 < 8; ++q2) {
            float4 r2 = red[q2][t];
            acc.x += r2.x; acc.y += r2.y; acc.z += r2.z; acc.w += r2.w;
        }
        int which = t >> 5, hh = t & 31;
        float4 base;
        if (which == 0) {
            base = s4[(size_t)node * 32 + hh];
        } else {
            ushort4 u = *(const ushort4*)&xv[(size_t)node * 768 + 384 + (size_t)(which - 1) * 128 + 4 * hh];
            base.x = bfu(u.x); base.y = bfu(u.y); base.z = bfu(u.z); base.w = bfu(u.w);
        }
        ushort4 o;
        o.x = bfround((base.x + acc.x) * EPSILON);
        o.y = bfround((base.y + acc.y) * EPSILON);
        o.z = bfround((base.z + acc.z) * EPSILON);
        o.w = bfround((base.w + acc.w) * EPSILON);
        *(ushort4*)&mid[(size_t)node * 512 + 4 * t] = o;
    }
}

// ---------------- K3 (MFMA): fused update; reads bf16 mid, writes fp32 out ----------------
__global__ __launch_bounds__(256, 3) void k3_mfma(
        const ushort_t* __restrict__ mid,
        const ushort_t* __restrict__ Wvp, const ushort_t* __restrict__ W1p,
        const ushort_t* __restrict__ W2p,
        const float* __restrict__ bm1, const float* __restrict__ bm2,
        float* __restrict__ out, int n_nodes) {
    // pool layout (bytes):
    //  Ab  @0      : v_mid bf16 48x136 = 13056   (phase0 -> final)
    //  vlb @13056  : v_l  bf16 48x136  = 13056   (gemm1 -> final)
    //  vrc @26112  : v_r  bf16 48x136  = 13056   (gemm1 -> phase2)
    //  Tb  @39168  : ts   bf16 16x264  =  8448   (phase2 -> gemm2)
    //  Hb  @47616  : h1   bf16 16x136  =  4352   (gemm2 -> gemm3)
    //  C3 f32 [16][400] overlays @26112..51712
    __shared__ __align__(16) char pool[51968];
    ushort_t* Ab  = (ushort_t*)pool;
    ushort_t* vlb = (ushort_t*)(pool + 13056);
    ushort_t* vrc = (ushort_t*)(pool + 26112);
    ushort_t* Tb  = (ushort_t*)(pool + 39168);
    ushort_t* Hb  = (ushort_t*)(pool + 47616);
    float* C3 = (float*)(pool + 26112);   // [16][400]

    int t = threadIdx.x;
    int node0 = blockIdx.x * 16;
    int wv = t >> 6, lane = t & 63;
    int g = lane >> 4, cl = lane & 15;

    float smid_reg[8], dot_reg[8];

    // phase 0: stage v_mid (48x128 bf16) via ushort4; s_mid -> registers
    #pragma unroll
    for (int i = 0; i < 6; ++i) {
        int flat4 = t + i * 256;          // ushort4 index over 48*32
        int row = flat4 >> 5, k4 = flat4 & 31;
        int n = row / 3, d = row - n * 3;
        int node = node0 + n; if (node >= n_nodes) node = n_nodes - 1;
        ushort4 u = *(const ushort4*)&mid[(size_t)node * 512 + (size_t)(1 + d) * 128 + 4 * k4];
        *(ushort4*)&Ab[row * 136 + 4 * k4] = u;
    }
    #pragma unroll
    for (int i = 0; i < 8; ++i) {
        int flat = t + i * 256;
        int n = flat >> 7, k = flat & 127;
        int node = node0 + n; if (node >= n_nodes) node = n_nodes - 1;
        smid_reg[i] = bfu(mid[(size_t)node * 512 + k]);
    }
    __syncthreads();

    // GEMM1: (48x128)@(128x256) -> v_l | v_r
    #pragma unroll
    for (int rt = 0; rt < 3; ++rt) {
        bf16x8 ah[4];
        #pragma unroll
        for (int ks = 0; ks < 4; ++ks)
            ah[ks] = *(const bf16x8*)&Ab[(rt * 16 + cl) * 136 + ks * 32 + g * 8];
        f32x4 acc[4] = {};
        #pragma unroll
        for (int ks = 0; ks < 4; ++ks) {
            #pragma unroll
            for (int c = 0; c < 4; ++c) {
                int ct = wv * 4 + c;
                bf16x8 bh = *(const bf16x8*)&Wvp[((size_t)(ks * 16 + ct) * 64 + lane) * 8];
                acc[c] = __builtin_amdgcn_mfma_f32_16x16x32_bf16(ah[ks], bh, acc[c], 0, 0, 0);
            }
        }
        #pragma unroll
        for (int c = 0; c < 4; ++c) {
            int col = (wv * 4 + c) * 16 + cl;
            ushort_t* dst = (col < 128) ? vlb : vrc;
            int cc = col & 127;
            #pragma unroll
            for (int r = 0; r < 4; ++r)
                dst[(rt * 16 + g * 4 + r) * 136 + cc] = bfround(acc[c][r]);
        }
    }
    __syncthreads();

    // phase 2: v_norm, dot -> regs; build ts
    #pragma unroll
    for (int i = 0; i < 8; ++i) {
        int flat = t + i * 256;
        int n = flat >> 7, h = flat & 127;
        float r0 = bfu(vrc[(3 * n + 0) * 136 + h]);
        float r1 = bfu(vrc[(3 * n + 1) * 136 + h]);
        float r2 = bfu(vrc[(3 * n + 2) * 136 + h]);
        float l0 = bfu(vlb[(3 * n + 0) * 136 + h]);
        float l1 = bfu(vlb[(3 * n + 1) * 136 + h]);
        float l2 = bfu(vlb[(3 * n + 2) * 136 + h]);
        float nrm = sqrtf(r0 * r0 + r1 * r1 + r2 * r2 + NEPS);
        dot_reg[i] = r0 * l0 + r1 * l1 + r2 * l2;
        Tb[n * 264 + 128 + h] = bfround(nrm);
        Tb[n * 264 + h] = bfround(smid_reg[i]);
    }
    __syncthreads();

    // GEMM2: (16x256)@(256x128) + bm1 -> silu -> h1
    f32x4 acc2[2] = {};
    #pragma unroll
    for (int ks = 0; ks < 8; ++ks) {
        bf16x8 ah = *(const bf16x8*)&Tb[cl * 264 + ks * 32 + g * 8];
        #pragma unroll
        for (int c = 0; c < 2; ++c) {
            int ct = wv * 2 + c;
            bf16x8 bh = *(const bf16x8*)&W1p[((size_t)(ks * 8 + ct) * 64 + lane) * 8];
            acc2[c] = __builtin_amdgcn_mfma_f32_16x16x32_bf16(ah, bh, acc2[c], 0, 0, 0);
        }
    }
    #pragma unroll
    for (int c = 0; c < 2; ++c) {
        int col = (wv * 2 + c) * 16 + cl;
        float bias = bm1[col];
        #pragma unroll
        for (int r = 0; r < 4; ++r) {
            int row = g * 4 + r;
            Hb[row * 136 + col] = bfround(silu_f(acc2[c][r] + bias));
        }
    }
    __syncthreads();

    // GEMM3: (16x128)@(128x384) + bm2 -> C3 (overlay)
    f32x4 acc3[6] = {};
    #pragma unroll
    for (int ks = 0; ks < 4; ++ks) {
        bf16x8 ah = *(const bf16x8*)&Hb[cl * 136 + ks * 32 + g * 8];
        #pragma unroll
        for (int c = 0; c < 6; ++c) {
            int ct = wv * 6 + c;
            bf16x8 bh = *(const bf16x8*)&W2p[((size_t)(ks * 24 + ct) * 64 + lane) * 8];
            acc3[c] = __builtin_amdgcn_mfma_f32_16x16x32_bf16(ah, bh, acc3[c], 0, 0, 0);
        }
    }
    __syncthreads();   // vrc/Tb/Hb reads done before overlay write
    #pragma unroll
    for (int c = 0; c < 6; ++c) {
        int col = (wv * 6 + c) * 16 + cl;
        float bias = bm2[col];
        #pragma unroll
        for (int r = 0; r < 4; ++r)
            C3[(g * 4 + r) * 400 + col] = acc3[c][r] + bias;
    }
    __syncthreads();

    // final combine
    #pragma unroll
    for (int i = 0; i < 8; ++i) {
        int flat = t + i * 256;
        int n = flat >> 7, h = flat & 127;
        int node = node0 + n;
        if (node >= n_nodes) continue;
        float ds_u = C3[n * 400 + h];
        float dv_u = C3[n * 400 + 128 + h];
        float dsv  = C3[n * 400 + 256 + h] * dot_reg[i];
        out[(size_t)node * 512 + h] = (smid_reg[i] + ds_u + dsv) * EPSILON;
        #pragma unroll
        for (int d = 0; d < 3; ++d) {
            int row = 3 * n + d;
            float vmid = bfu(Ab[row * 136 + h]);
            float vl_v = bfu(vlb[row * 136 + h]);
            out[(size_t)node * 512 + 128 + d * 128 + h] = (vmid + vl_v * dv_u) * EPSILON;
        }
    }
}

static inline size_t align_up(size_t x, size_t a) { return (x + a - 1) / a * a; }

extern "C" void kernel_launch(void* const* d_in, const int* in_sizes, int n_in,
                              void* d_out, int out_size, void* d_ws, size_t ws_size,
                              hipStream_t stream) {
    const float* s       = (const float*)d_in[0];
    const float* v       = (const float*)d_in[1];
    const float* dir     = (const float*)d_in[2];
    const float* Wij     = (const float*)d_in[3];
    const int*   senders = (const int*)d_in[4];
    const int*   recv    = (const int*)d_in[5];
    const float* Wi1     = (const float*)d_in[6];
    const float* bi1     = (const float*)d_in[7];
    const float* Wi2     = (const float*)d_in[8];
    const float* bi2     = (const float*)d_in[9];
    const float* Wm1     = (const float*)d_in[10];
    const float* bm1     = (const float*)d_in[11];
    const float* Wm2     = (const float*)d_in[12];
    const float* bm2     = (const float*)d_in[13];
    const float* Wvm     = (const float*)d_in[14];

    int n_nodes = in_sizes[0] / H;
    int n_edges = in_sizes[4];
    float* out = (float*)d_out;

    // workspace layout
    char* ws = (char*)d_ws;
    size_t off = 0;
    ushort_t* xv  = (ushort_t*)(ws + off); off = align_up(off + (size_t)n_nodes * 768 * 2, 256);
    ushort_t* mid = (ushort_t*)(ws + off); off = align_up(off + (size_t)n_nodes * 512 * 2, 256);
    int* starts = (int*)(ws + off); off = align_up(off + (size_t)n_nodes * 4, 256);
    int* cnt    = (int*)(ws + off); off = align_up(off + (size_t)(n_nodes + 1) * 4, 256);
    int* cursor = cnt + n_nodes;
    int* head   = (int*)(ws + off); off = align_up(off + (size_t)n_nodes * 4, 256);
    int2* epair = (int2*)(ws + off); off = align_up(off + (size_t)n_edges * 8, 256);
    ushort_t* Wi1p = (ushort_t*)(ws + off); off = align_up(off + 16384 * 2, 256);
    ushort_t* Wi2p = (ushort_t*)(ws + off); off = align_up(off + 49152 * 2, 256);
    ushort_t* Wvp  = (ushort_t*)(ws + off); off = align_up(off + 32768 * 2, 256);
    ushort_t* Wm1p = (ushort_t*)(ws + off); off = align_up(off + 32768 * 2, 256);
    ushort_t* Wm2p = (ushort_t*)(ws + off); off = align_up(off + 49152 * 2, 256);
    if (off > ws_size) return;   // ws is ~3.6 GB; always fits

    // prep: zero cnt+cursor, pack weights, convert v into xv (one launch)
    int n4 = n_nodes * 96;
    int prep_total = (n_nodes + 1) + 16384 + 49152 + 32768 + 32768 + 49152 + n4;
    int prep_blocks = (prep_total + 255) / 256;
    if (prep_blocks > 2048) prep_blocks = 2048;
    k_prep<<<prep_blocks, 256, 0, stream>>>(
        Wi1, Wi2, Wvm, Wm1, Wm2, Wi1p, Wi2p, Wvp, Wm1p, Wm2p,
        (const float4*)v, xv, cnt, n_nodes + 1, n4);

    // CSR build
    k_hist<<<(n_edges + 255) / 256, 256, 0, stream>>>(senders, cnt, n_edges);
    k_alloc<<<(n_nodes + 255) / 256, 256, 0, stream>>>(cnt, starts, head, cursor, n_nodes);
    k_scatter<<<(n_edges + 255) / 256, 256, 0, stream>>>(senders, recv, head, epair, n_edges);

    k1_mfma<<<(n_nodes + 15) / 16, 256, 0, stream>>>(
        s, Wi1p, Wi2p, bi1, bi2, xv, n_nodes);

    k2_csr<<<n_nodes, 256, 0, stream>>>(
        (const float4*)s, xv, dir,
        (const float4*)Wij, starts, cnt, epair, mid, n_nodes);

    k3_mfma<<<(n_nodes + 15) / 16, 256, 0, stream>>>(
        mid, Wvp, Wm1p, Wm2p, bm1, bm2, out, n_nodes);
}

// Round 9
// 451.996 us; speedup vs baseline: 4.2678x; 1.0548x over previous
//
#include <hip/hip_runtime.h>

#define H 128
#define EPSILON 0.7071067811865476f
#define NEPS 1e-8f

typedef short bf16x8 __attribute__((ext_vector_type(8)));
typedef float f32x4 __attribute__((ext_vector_type(4)));
typedef unsigned short ushort_t;

__device__ __forceinline__ float silu_f(float x) {
    return x / (1.0f + __expf(-x));
}
__device__ __forceinline__ unsigned short bfround(float w) {
    unsigned ub = __float_as_uint(w);
    return (unsigned short)((ub + 0x7FFF + ((ub >> 16) & 1)) >> 16);
}
__device__ __forceinline__ float bfu(unsigned short u) { return __uint_as_float(((unsigned)u) << 16); }

// pack one element of a K x N weight into fragment-major bf16
// elem (ks, ct, lane, j) at ((ks*CT+ct)*64+lane)*8+j = W[ks*32+(lane>>4)*8+j][ct*16+(lane&15)]
__device__ __forceinline__ void pack_one(const float* __restrict__ W, int N,
                                         ushort_t* __restrict__ p, int tid) {
    int CT = N >> 4;
    int j = tid & 7;
    int l = (tid >> 3) & 63;
    int rest = tid >> 9;
    int ct = rest % CT;
    int ks = rest / CT;
    int row = ks * 32 + ((l >> 4) << 3) + j;
    int col = ct * 16 + (l & 15);
    p[tid] = bfround(W[(size_t)row * N + col]);
}

// ---------------- K_prep: zero cnt + pack 5 weights ----------------
__global__ void k_prep(const float* __restrict__ Wi1, const float* __restrict__ Wi2,
                       const float* __restrict__ Wvm, const float* __restrict__ Wm1,
                       const float* __restrict__ Wm2,
                       ushort_t* __restrict__ Wi1p, ushort_t* __restrict__ Wi2p,
                       ushort_t* __restrict__ Wvp, ushort_t* __restrict__ Wm1p,
                       ushort_t* __restrict__ Wm2p,
                       int* __restrict__ cnt, int n_cnt) {
    int gid = blockIdx.x * blockDim.x + threadIdx.x;
    int stride = gridDim.x * blockDim.x;
    int S0 = n_cnt;
    int S1 = S0 + 16384;
    int S2 = S1 + 49152;
    int S3 = S2 + 32768;
    int S4 = S3 + 32768;
    int S5 = S4 + 49152;
    for (int i = gid; i < S5; i += stride) {
        if (i < S0)      cnt[i] = 0;
        else if (i < S1) pack_one(Wi1, 128, Wi1p, i - S0);
        else if (i < S2) pack_one(Wi2, 384, Wi2p, i - S1);
        else if (i < S3) pack_one(Wvm, 256, Wvp,  i - S2);
        else if (i < S4) pack_one(Wm1, 128, Wm1p, i - S3);
        else             pack_one(Wm2, 384, Wm2p, i - S4);
    }
}

// ---------------- K1 (MFMA): x = silu(s@Wi1+bi1)@Wi2+bi2 -> xv[0:384]; also v -> xv[384:768] ----------------
__global__ __launch_bounds__(256, 6) void k1_mfma(
        const float* __restrict__ s, const float4* __restrict__ v4,
        const ushort_t* __restrict__ W1p, const ushort_t* __restrict__ W2p,
        const float* __restrict__ bi1, const float* __restrict__ bi2,
        ushort_t* __restrict__ xv, int n_nodes) {
    __shared__ ushort_t Ab[16 * 136];
    __shared__ ushort_t Hb[16 * 136];
    int t = threadIdx.x;
    int node0 = blockIdx.x * 16;
    int wv = t >> 6, lane = t & 63;
    int g = lane >> 4, cl = lane & 15;

    #pragma unroll
    for (int i = 0; i < 8; ++i) {
        int flat = t + i * 256;
        int n = flat >> 7, k = flat & 127;
        int node = node0 + n; if (node >= n_nodes) node = n_nodes - 1;
        Ab[n * 136 + k] = bfround(s[(size_t)node * 128 + k]);
    }
    __syncthreads();

    f32x4 acc1[2] = {};
    #pragma unroll
    for (int ks = 0; ks < 4; ++ks) {
        bf16x8 ah = *(const bf16x8*)&Ab[cl * 136 + ks * 32 + g * 8];
        #pragma unroll
        for (int c = 0; c < 2; ++c) {
            int ct = wv * 2 + c;
            bf16x8 bh = *(const bf16x8*)&W1p[((size_t)(ks * 8 + ct) * 64 + lane) * 8];
            acc1[c] = __builtin_amdgcn_mfma_f32_16x16x32_bf16(ah, bh, acc1[c], 0, 0, 0);
        }
    }
    #pragma unroll
    for (int c = 0; c < 2; ++c) {
        int col = (wv * 2 + c) * 16 + cl;
        float bias = bi1[col];
        #pragma unroll
        for (int r = 0; r < 4; ++r) {
            int row = g * 4 + r;
            Hb[row * 136 + col] = bfround(silu_f(acc1[c][r] + bias));
        }
    }
    __syncthreads();

    f32x4 acc2[6] = {};
    #pragma unroll
    for (int ks = 0; ks < 4; ++ks) {
        bf16x8 ah = *(const bf16x8*)&Hb[cl * 136 + ks * 32 + g * 8];
        #pragma unroll
        for (int c = 0; c < 6; ++c) {
            int ct = wv * 6 + c;
            bf16x8 bh = *(const bf16x8*)&W2p[((size_t)(ks * 24 + ct) * 64 + lane) * 8];
            acc2[c] = __builtin_amdgcn_mfma_f32_16x16x32_bf16(ah, bh, acc2[c], 0, 0, 0);
        }
    }
    #pragma unroll
    for (int c = 0; c < 6; ++c) {
        int col = (wv * 6 + c) * 16 + cl;
        float bias = bi2[col];
        #pragma unroll
        for (int r = 0; r < 4; ++r) {
            int node = node0 + g * 4 + r;
            if (node < n_nodes) xv[(size_t)node * 768 + col] = bfround(acc2[c][r] + bias);
        }
    }

    // convert these 16 nodes' v rows -> xv[384:768] (independent of MLP above)
    #pragma unroll
    for (int i = 0; i < 6; ++i) {
        int flat = t + i * 256;               // 0..1535 = 16 nodes * 96 float4
        int n = flat / 96, part = flat - n * 96;
        int node = node0 + n;
        if (node < n_nodes) {
            float4 f = v4[(size_t)node * 96 + part];
            ushort4 u;
            u.x = bfround(f.x); u.y = bfround(f.y); u.z = bfround(f.z); u.w = bfround(f.w);
            *(ushort4*)&xv[(size_t)node * 768 + 384 + 4 * part] = u;
        }
    }
}

// ---------------- CSR build ----------------
__global__ void k_hist(const int* __restrict__ senders, int* __restrict__ cnt, int n_edges) {
    int e = blockIdx.x * blockDim.x + threadIdx.x;
    if (e < n_edges) atomicAdd(&cnt[senders[e]], 1);
}

__global__ void k_alloc(const int* __restrict__ cnt, int* __restrict__ starts,
                        int* __restrict__ head, int* __restrict__ cursor, int n) {
    int i = blockIdx.x * blockDim.x + threadIdx.x;
    int lane = threadIdx.x & 63;
    int c = (i < n) ? cnt[i] : 0;
    int pref = c;
    #pragma unroll
    for (int off = 1; off < 64; off <<= 1) {
        int up = __shfl_up(pref, off, 64);
        if (lane >= off) pref += up;
    }
    int total = __shfl(pref, 63, 64);
    int base = 0;
    if (lane == 63) base = atomicAdd(cursor, total);
    base = __shfl(base, 63, 64);
    if (i < n) { int p = base + pref - c; starts[i] = p; head[i] = p; }
}

__global__ void k_scatter(const int* __restrict__ senders, const int* __restrict__ receivers,
                          const float* __restrict__ dir, int* __restrict__ head,
                          int* __restrict__ eord, float4* __restrict__ edir, int n_edges) {
    int e = blockIdx.x * blockDim.x + threadIdx.x;
    if (e < n_edges) {
        int p = atomicAdd(&head[senders[e]], 1);
        eord[p] = e;
        float4 ed;
        ed.x = dir[3 * (size_t)e + 0];
        ed.y = dir[3 * (size_t)e + 1];
        ed.z = dir[3 * (size_t)e + 2];
        ed.w = __int_as_float(receivers[e]);
        edir[p] = ed;
    }
}

// ---------------- K2 (CSR): per-node gather-accumulate -> bf16 mid ----------------
__global__ __launch_bounds__(256) void k2_csr(
        const float4* __restrict__ s4, const ushort_t* __restrict__ xv,
        const float* __restrict__ wf, const int* __restrict__ starts,
        const int* __restrict__ cnt, const int* __restrict__ eord,
        const float4* __restrict__ edir, ushort_t* __restrict__ mid, int n_nodes) {
    __shared__ float4 red[8][128];
    int node = blockIdx.x;
    int t = threadIdx.x;
    int slot = t >> 5, lane = t & 31;
    int beg = starts[node], num = cnt[node];
    float4 ds  = {0.f, 0.f, 0.f, 0.f};
    float4 dv0 = {0.f, 0.f, 0.f, 0.f};
    float4 dv1 = {0.f, 0.f, 0.f, 0.f};
    float4 dv2 = {0.f, 0.f, 0.f, 0.f};
    for (int q = slot; q < num; q += 8) {
        int e = eord[beg + q];
        float4 ed = edir[beg + q];
        int r = __float_as_int(ed.w);
        const f32x4*    we  = (const f32x4*)(wf + (size_t)e * 384);
        const ushort_t* xvr = xv + (size_t)r * 768;
        // non-temporal: Wij is a 922 MB read-once stream; don't evict xv from L2/L3
        f32x4 wa = __builtin_nontemporal_load(we + lane);
        f32x4 wb = __builtin_nontemporal_load(we + 32 + lane);
        f32x4 wc = __builtin_nontemporal_load(we + 64 + lane);
        ushort4 xa = *(const ushort4*)&xvr[4 * lane];
        ushort4 xb = *(const ushort4*)&xvr[128 + 4 * lane];
        ushort4 xc = *(const ushort4*)&xvr[256 + 4 * lane];
        ushort4 va = *(const ushort4*)&xvr[384 + 4 * lane];
        ushort4 vb = *(const ushort4*)&xvr[512 + 4 * lane];
        ushort4 vc = *(const ushort4*)&xvr[640 + 4 * lane];
        float bx = wb[0] * bfu(xb.x), by = wb[1] * bfu(xb.y), bz = wb[2] * bfu(xb.z), bw = wb[3] * bfu(xb.w);
        float cx = wc[0] * bfu(xc.x), cy = wc[1] * bfu(xc.y), cz = wc[2] * bfu(xc.z), cw = wc[3] * bfu(xc.w);
        ds.x += wa[0] * bfu(xa.x); ds.y += wa[1] * bfu(xa.y);
        ds.z += wa[2] * bfu(xa.z); ds.w += wa[3] * bfu(xa.w);
        dv0.x += bx * ed.x + cx * bfu(va.x); dv0.y += by * ed.x + cy * bfu(va.y);
        dv0.z += bz * ed.x + cz * bfu(va.z); dv0.w += bw * ed.x + cw * bfu(va.w);
        dv1.x += bx * ed.y + cx * bfu(vb.x); dv1.y += by * ed.y + cy * bfu(vb.y);
        dv1.z += bz * ed.y + cz * bfu(vb.z); dv1.w += bw * ed.y + cw * bfu(vb.w);
        dv2.x += bx * ed.z + cx * bfu(vc.x); dv2.y += by * ed.z + cy * bfu(vc.y);
        dv2.z += bz * ed.z + cz * bfu(vc.z); dv2.w += bw * ed.z + cw * bfu(vc.w);
    }
    red[slot][lane]      = ds;
    red[slot][32 + lane] = dv0;
    red[slot][64 + lane] = dv1;
    red[slot][96 + lane] = dv2;
    __syncthreads();
    if (t < 128) {
        float4 acc = red[0][t];
        #pragma unroll
        for (int q2 = 1; q2 < 8; ++q2) {
            float4 r2 = red[q2][t];
            acc.x += r2.x; acc.y += r2.y; acc.z += r2.z; acc.w += r2.w;
        }
        int which = t >> 5, hh = t & 31;
        float4 base;
        if (which == 0) {
            base = s4[(size_t)node * 32 + hh];
        } else {
            ushort4 u = *(const ushort4*)&xv[(size_t)node * 768 + 384 + (size_t)(which - 1) * 128 + 4 * hh];
            base.x = bfu(u.x); base.y = bfu(u.y); base.z = bfu(u.z); base.w = bfu(u.w);
        }
        ushort4 o;
        o.x = bfround((base.x + acc.x) * EPSILON);
        o.y = bfround((base.y + acc.y) * EPSILON);
        o.z = bfround((base.z + acc.z) * EPSILON);
        o.w = bfround((base.w + acc.w) * EPSILON);
        *(ushort4*)&mid[(size_t)node * 512 + 4 * t] = o;
    }
}

// ---------------- K3 (MFMA): fused update; reads bf16 mid, writes fp32 out ----------------
__global__ __launch_bounds__(256, 3) void k3_mfma(
        const ushort_t* __restrict__ mid,
        const ushort_t* __restrict__ Wvp, const ushort_t* __restrict__ W1p,
        const ushort_t* __restrict__ W2p,
        const float* __restrict__ bm1, const float* __restrict__ bm2,
        float* __restrict__ out, int n_nodes) {
    // pool layout (bytes):
    //  Ab  @0      : v_mid bf16 48x136 = 13056   (phase0 -> final)
    //  vlb @13056  : v_l  bf16 48x136  = 13056   (gemm1 -> final)
    //  vrc @26112  : v_r  bf16 48x136  = 13056   (gemm1 -> phase2)
    //  Tb  @39168  : ts   bf16 16x264  =  8448   (phase2 -> gemm2)
    //  Hb  @47616  : h1   bf16 16x136  =  4352   (gemm2 -> gemm3)
    //  C3 f32 [16][400] overlays @26112..51712
    __shared__ __align__(16) char pool[51968];
    ushort_t* Ab  = (ushort_t*)pool;
    ushort_t* vlb = (ushort_t*)(pool + 13056);
    ushort_t* vrc = (ushort_t*)(pool + 26112);
    ushort_t* Tb  = (ushort_t*)(pool + 39168);
    ushort_t* Hb  = (ushort_t*)(pool + 47616);
    float* C3 = (float*)(pool + 26112);   // [16][400]

    int t = threadIdx.x;
    int node0 = blockIdx.x * 16;
    int wv = t >> 6, lane = t & 63;
    int g = lane >> 4, cl = lane & 15;

    float smid_reg[8], dot_reg[8];

    // phase 0: stage v_mid (48x128 bf16) via ushort4; s_mid -> registers
    #pragma unroll
    for (int i = 0; i < 6; ++i) {
        int flat4 = t + i * 256;          // ushort4 index over 48*32
        int row = flat4 >> 5, k4 = flat4 & 31;
        int n = row / 3, d = row - n * 3;
        int node = node0 + n; if (node >= n_nodes) node = n_nodes - 1;
        ushort4 u = *(const ushort4*)&mid[(size_t)node * 512 + (size_t)(1 + d) * 128 + 4 * k4];
        *(ushort4*)&Ab[row * 136 + 4 * k4] = u;
    }
    #pragma unroll
    for (int i = 0; i < 8; ++i) {
        int flat = t + i * 256;
        int n = flat >> 7, k = flat & 127;
        int node = node0 + n; if (node >= n_nodes) node = n_nodes - 1;
        smid_reg[i] = bfu(mid[(size_t)node * 512 + k]);
    }
    __syncthreads();

    // GEMM1: (48x128)@(128x256) -> v_l | v_r
    #pragma unroll
    for (int rt = 0; rt < 3; ++rt) {
        bf16x8 ah[4];
        #pragma unroll
        for (int ks = 0; ks < 4; ++ks)
            ah[ks] = *(const bf16x8*)&Ab[(rt * 16 + cl) * 136 + ks * 32 + g * 8];
        f32x4 acc[4] = {};
        #pragma unroll
        for (int ks = 0; ks < 4; ++ks) {
            #pragma unroll
            for (int c = 0; c < 4; ++c) {
                int ct = wv * 4 + c;
                bf16x8 bh = *(const bf16x8*)&Wvp[((size_t)(ks * 16 + ct) * 64 + lane) * 8];
                acc[c] = __builtin_amdgcn_mfma_f32_16x16x32_bf16(ah[ks], bh, acc[c], 0, 0, 0);
            }
        }
        #pragma unroll
        for (int c = 0; c < 4; ++c) {
            int col = (wv * 4 + c) * 16 + cl;
            ushort_t* dst = (col < 128) ? vlb : vrc;
            int cc = col & 127;
            #pragma unroll
            for (int r = 0; r < 4; ++r)
                dst[(rt * 16 + g * 4 + r) * 136 + cc] = bfround(acc[c][r]);
        }
    }
    __syncthreads();

    // phase 2: v_norm, dot -> regs; build ts
    #pragma unroll
    for (int i = 0; i < 8; ++i) {
        int flat = t + i * 256;
        int n = flat >> 7, h = flat & 127;
        float r0 = bfu(vrc[(3 * n + 0) * 136 + h]);
        float r1 = bfu(vrc[(3 * n + 1) * 136 + h]);
        float r2 = bfu(vrc[(3 * n + 2) * 136 + h]);
        float l0 = bfu(vlb[(3 * n + 0) * 136 + h]);
        float l1 = bfu(vlb[(3 * n + 1) * 136 + h]);
        float l2 = bfu(vlb[(3 * n + 2) * 136 + h]);
        float nrm = sqrtf(r0 * r0 + r1 * r1 + r2 * r2 + NEPS);
        dot_reg[i] = r0 * l0 + r1 * l1 + r2 * l2;
        Tb[n * 264 + 128 + h] = bfround(nrm);
        Tb[n * 264 + h] = bfround(smid_reg[i]);
    }
    __syncthreads();

    // GEMM2: (16x256)@(256x128) + bm1 -> silu -> h1
    f32x4 acc2[2] = {};
    #pragma unroll
    for (int ks = 0; ks < 8; ++ks) {
        bf16x8 ah = *(const bf16x8*)&Tb[cl * 264 + ks * 32 + g * 8];
        #pragma unroll
        for (int c = 0; c < 2; ++c) {
            int ct = wv * 2 + c;
            bf16x8 bh = *(const bf16x8*)&W1p[((size_t)(ks * 8 + ct) * 64 + lane) * 8];
            acc2[c] = __builtin_amdgcn_mfma_f32_16x16x32_bf16(ah, bh, acc2[c], 0, 0, 0);
        }
    }
    #pragma unroll
    for (int c = 0; c < 2; ++c) {
        int col = (wv * 2 + c) * 16 + cl;
        float bias = bm1[col];
        #pragma unroll
        for (int r = 0; r < 4; ++r) {
            int row = g * 4 + r;
            Hb[row * 136 + col] = bfround(silu_f(acc2[c][r] + bias));
        }
    }
    __syncthreads();

    // GEMM3: (16x128)@(128x384) + bm2 -> C3 (overlay)
    f32x4 acc3[6] = {};
    #pragma unroll
    for (int ks = 0; ks < 4; ++ks) {
        bf16x8 ah = *(const bf16x8*)&Hb[cl * 136 + ks * 32 + g * 8];
        #pragma unroll
        for (int c = 0; c < 6; ++c) {
            int ct = wv * 6 + c;
            bf16x8 bh = *(const bf16x8*)&W2p[((size_t)(ks * 24 + ct) * 64 + lane) * 8];
            acc3[c] = __builtin_amdgcn_mfma_f32_16x16x32_bf16(ah, bh, acc3[c], 0, 0, 0);
        }
    }
    __syncthreads();   // vrc/Tb/Hb reads done before overlay write
    #pragma unroll
    for (int c = 0; c < 6; ++c) {
        int col = (wv * 6 + c) * 16 + cl;
        float bias = bm2[col];
        #pragma unroll
        for (int r = 0; r < 4; ++r)
            C3[(g * 4 + r) * 400 + col] = acc3[c][r] + bias;
    }
    __syncthreads();

    // final combine (non-temporal stores: out is write-once)
    #pragma unroll
    for (int i = 0; i < 8; ++i) {
        int flat = t + i * 256;
        int n = flat >> 7, h = flat & 127;
        int node = node0 + n;
        if (node >= n_nodes) continue;
        float ds_u = C3[n * 400 + h];
        float dv_u = C3[n * 400 + 128 + h];
        float dsv  = C3[n * 400 + 256 + h] * dot_reg[i];
        __builtin_nontemporal_store((smid_reg[i] + ds_u + dsv) * EPSILON,
                                    &out[(size_t)node * 512 + h]);
        #pragma unroll
        for (int d = 0; d < 3; ++d) {
            int row = 3 * n + d;
            float vmid = bfu(Ab[row * 136 + h]);
            float vl_v = bfu(vlb[row * 136 + h]);
            __builtin_nontemporal_store((vmid + vl_v * dv_u) * EPSILON,
                                        &out[(size_t)node * 512 + 128 + d * 128 + h]);
        }
    }
}

static inline size_t align_up(size_t x, size_t a) { return (x + a - 1) / a * a; }

extern "C" void kernel_launch(void* const* d_in, const int* in_sizes, int n_in,
                              void* d_out, int out_size, void* d_ws, size_t ws_size,
                              hipStream_t stream) {
    const float* s       = (const float*)d_in[0];
    const float* v       = (const float*)d_in[1];
    const float* dir     = (const float*)d_in[2];
    const float* Wij     = (const float*)d_in[3];
    const int*   senders = (const int*)d_in[4];
    const int*   recv    = (const int*)d_in[5];
    const float* Wi1     = (const float*)d_in[6];
    const float* bi1     = (const float*)d_in[7];
    const float* Wi2     = (const float*)d_in[8];
    const float* bi2     = (const float*)d_in[9];
    const float* Wm1     = (const float*)d_in[10];
    const float* bm1     = (const float*)d_in[11];
    const float* Wm2     = (const float*)d_in[12];
    const float* bm2     = (const float*)d_in[13];
    const float* Wvm     = (const float*)d_in[14];

    int n_nodes = in_sizes[0] / H;
    int n_edges = in_sizes[4];
    float* out = (float*)d_out;

    // workspace layout
    char* ws = (char*)d_ws;
    size_t off = 0;
    ushort_t* xv  = (ushort_t*)(ws + off); off = align_up(off + (size_t)n_nodes * 768 * 2, 256);
    ushort_t* mid = (ushort_t*)(ws + off); off = align_up(off + (size_t)n_nodes * 512 * 2, 256);
    int* starts = (int*)(ws + off); off = align_up(off + (size_t)n_nodes * 4, 256);
    int* cnt    = (int*)(ws + off); off = align_up(off + (size_t)(n_nodes + 1) * 4, 256);
    int* cursor = cnt + n_nodes;
    int* head   = (int*)(ws + off); off = align_up(off + (size_t)n_nodes * 4, 256);
    int* eord   = (int*)(ws + off); off = align_up(off + (size_t)n_edges * 4, 256);
    float4* edir = (float4*)(ws + off); off = align_up(off + (size_t)n_edges * 16, 256);
    ushort_t* Wi1p = (ushort_t*)(ws + off); off = align_up(off + 16384 * 2, 256);
    ushort_t* Wi2p = (ushort_t*)(ws + off); off = align_up(off + 49152 * 2, 256);
    ushort_t* Wvp  = (ushort_t*)(ws + off); off = align_up(off + 32768 * 2, 256);
    ushort_t* Wm1p = (ushort_t*)(ws + off); off = align_up(off + 32768 * 2, 256);
    ushort_t* Wm2p = (ushort_t*)(ws + off); off = align_up(off + 49152 * 2, 256);
    if (off > ws_size) return;   // ws is ~3.6 GB; always fits

    // prep: zero cnt+cursor, pack weights
    int prep_total = (n_nodes + 1) + 16384 + 49152 + 32768 + 32768 + 49152;
    k_prep<<<(prep_total + 255) / 256, 256, 0, stream>>>(
        Wi1, Wi2, Wvm, Wm1, Wm2, Wi1p, Wi2p, Wvp, Wm1p, Wm2p, cnt, n_nodes + 1);

    // CSR build
    k_hist<<<(n_edges + 255) / 256, 256, 0, stream>>>(senders, cnt, n_edges);
    k_alloc<<<(n_nodes + 255) / 256, 256, 0, stream>>>(cnt, starts, head, cursor, n_nodes);
    k_scatter<<<(n_edges + 255) / 256, 256, 0, stream>>>(senders, recv, dir, head, eord, edir, n_edges);

    k1_mfma<<<(n_nodes + 15) / 16, 256, 0, stream>>>(
        s, (const float4*)v, Wi1p, Wi2p, bi1, bi2, xv, n_nodes);

    k2_csr<<<n_nodes, 256, 0, stream>>>(
        (const float4*)s, xv, Wij, starts, cnt, eord, edir, mid, n_nodes);

    k3_mfma<<<(n_nodes + 15) / 16, 256, 0, stream>>>(
        mid, Wvp, Wm1p, Wm2p, bm1, bm2, out, n_nodes);
}